// Round 9
// baseline (585.616 us; speedup 1.0000x reference)
//
#include <hip/hip_runtime.h>
#include <hip/hip_fp16.h>

#define SQ   4096
#define DIMM 2048
#define QKVN 4096   // 2048 q | 1024 k | 1024 v

typedef unsigned short u16;
typedef unsigned int u32;
typedef __attribute__((ext_vector_type(8))) short    short8;  // bf16x8 frag
typedef __attribute__((ext_vector_type(8))) _Float16 half8;   // f16x8 frag
typedef __attribute__((ext_vector_type(4))) float    f32x4;

__device__ __forceinline__ u16 f2bf(float f) {
  u32 u = __float_as_uint(f);
  u32 r = u + 0x7fffu + ((u >> 16) & 1u);
  return (u16)(r >> 16);
}
__device__ __forceinline__ float bf2f(u16 h) { return __uint_as_float(((u32)h) << 16); }
__device__ __forceinline__ u16 f2h(float f) { return __half_as_ushort(__float2half(f)); }
__device__ __forceinline__ float h2f(u16 h) { union { u16 u; _Float16 f; } c; c.u = h; return (float)c.f; }

__device__ __forceinline__ void gll16(const void* g, void* l) {
  __builtin_amdgcn_global_load_lds((const __attribute__((address_space(1))) void*)g,
                                   (__attribute__((address_space(3))) void*)l, 16, 0, 0);
}

// chunk-slot cumulative index per head: chunks of 8 KV blocks (128-token units)
__device__ __host__ __forceinline__ int cidx(int qb) {
  return qb < 8 ? qb : qb < 16 ? 8 + (qb - 8) * 2 : qb < 24 ? 24 + (qb - 16) * 3 : 48 + (qb - 24) * 4;
}

// ---------------- RoPE tables (double-accurate, rounded to fp32) ----------------
__global__ __launch_bounds__(256) void k_tables(float* __restrict__ cosb, float* __restrict__ sinb) {
  int idx = blockIdx.x * 256 + threadIdx.x;  // SQ*64
  int pos = idx >> 6, i = idx & 63;
  double f = 1.0 / pow(10000.0, (double)i / 64.0);
  float inv = (float)f;
  float ang = (float)pos * inv;
  cosb[idx] = (float)cos((double)ang);
  sinb[idx] = (float)sin((double)ang);
}

// ---------------- split x into bf16 hi/lo ----------------
__global__ __launch_bounds__(256) void k_split_x(const float* __restrict__ x,
                                                 u16* __restrict__ xh, u16* __restrict__ xl) {
  size_t base = ((size_t)blockIdx.x * 256 + threadIdx.x) * 4;
  float4 v = *(const float4*)(x + base);
  float vv[4] = {v.x, v.y, v.z, v.w};
  u16 hh[4], ll[4];
#pragma unroll
  for (int j = 0; j < 4; j++) {
    hh[j] = f2bf(vv[j]);
    ll[j] = f2bf(vv[j] - bf2f(hh[j]));
  }
  *(uint2*)(xh + base) = make_uint2((u32)hh[0] | ((u32)hh[1] << 16), (u32)hh[2] | ((u32)hh[3] << 16));
  *(uint2*)(xl + base) = make_uint2((u32)ll[0] | ((u32)ll[1] << 16), (u32)ll[2] | ((u32)ll[3] << 16));
}

// ---------------- transpose W (KxN) -> WT (NxK) with bf16 hi/lo split ----------------
__global__ __launch_bounds__(256) void k_trans_split(const float* __restrict__ src, int N,
                                                     u16* __restrict__ dh, u16* __restrict__ dl,
                                                     int rowOff) {
  __shared__ float t[64][65];
  int n0 = blockIdx.x * 64, k0 = blockIdx.y * 64;
  int tid = threadIdx.x;
  int c = tid & 63, r4 = tid >> 6;
#pragma unroll
  for (int it = 0; it < 16; it++) {
    int kk = it * 4 + r4;
    t[kk][c] = src[(size_t)(k0 + kk) * N + n0 + c];
  }
  __syncthreads();
#pragma unroll
  for (int it = 0; it < 16; it++) {
    int nn = it * 4 + r4;
    float v = t[c][nn];
    u16 hh = f2bf(v);
    size_t o = (size_t)(rowOff + n0 + nn) * 2048 + k0 + c;
    dh[o] = hh;
    dl[o] = f2bf(v - bf2f(hh));
  }
}

// ---------------- transpose wo (KxN fp32) -> woT (NxK f16) ----------------
__global__ __launch_bounds__(256) void k_trans_f16(const float* __restrict__ src, int N,
                                                   u16* __restrict__ dst) {
  __shared__ float t[64][65];
  int n0 = blockIdx.x * 64, k0 = blockIdx.y * 64;
  int tid = threadIdx.x;
  int c = tid & 63, r4 = tid >> 6;
#pragma unroll
  for (int it = 0; it < 16; it++) {
    int kk = it * 4 + r4;
    t[kk][c] = src[(size_t)(k0 + kk) * N + n0 + c];
  }
  __syncthreads();
#pragma unroll
  for (int it = 0; it < 16; it++) {
    int nn = it * 4 + r4;
    dst[(size_t)(n0 + nn) * 2048 + k0 + c] = f2h(t[c][nn]);
  }
}

// ---------------- QKV projection: bf16x3 split GEMM, 128x256 tile, BK=32,
// 3-buffer LDS ring (144KB dynamic), depth-2 prefetch with COUNTED vmcnt (T4):
// per step: s_waitcnt vmcnt(6) -> raw s_barrier -> stage(ks+2) -> ds_read+48 MFMA.
// Loads for tile k stay in flight across ~2 steps; never drains to 0 until the end.
// XCD mapping: 4 m-tiles pinned per XCD (A panels L2-resident). ----------------
__global__ __launch_bounds__(512) void k_gemm_qkv(
    const u16* __restrict__ xh, const u16* __restrict__ xl,
    const u16* __restrict__ wth, const u16* __restrict__ wtl,
    float* __restrict__ qkv) {
  extern __shared__ u16 lds[];          // 3 bufs x 24576 u16 (48KB): Ah|Al|Bh|Bl
  const int tid = threadIdx.x;
  const int lane = tid & 63, wid = tid >> 6;     // 8 waves
  const int rg = lane >> 4, c16 = lane & 15;
  const int bid0 = blockIdx.x;                   // 512 blocks
  const int xcd = bid0 & 7, local = bid0 >> 3;   // local in [0,64)
  const int m0 = (xcd * 4 + (local & 3)) * 128;  // m-tiles pinned per XCD
  const int n0 = (local >> 2) * 256;             // 16 n-tiles of 256
  const int wm = wid >> 2, wn = wid & 3;         // 2m x 4n waves (64x64 out each)
  const int srow4 = lane >> 2;                   // row within 16-row group
  const int pc = lane & 3;                       // 16B chunk within 64B row

  f32x4 acc[4][4];
#pragma unroll
  for (int a = 0; a < 4; a++)
#pragma unroll
    for (int b = 0; b < 4; b++) acc[a][b] = (f32x4){0.f, 0.f, 0.f, 0.f};

  // 48 gll16 per buf = 6 per wave. op o: [0,8)=Ah grp, [8,16)=Al, [16,32)=Bh, [32,48)=Bl.
  // LDS dest wave-uniform (HW adds lane*16B); global source inverse-XOR-swizzled (rule #21).
  auto stage = [&](int bi, int k0) {
    u16* base = lds + bi * 24576;
#pragma unroll
    for (int i = 0; i < 6; i++) {
      int o = wid * 6 + i;
      int grp = (o < 8) ? o : (o < 16) ? (o - 8) : (o < 32) ? (o - 16) : (o - 32);
      int row = grp * 16 + srow4;
      int cl = (pc ^ ((row >> 1) & 3)) * 8;
      const u16* g;
      u16* d;
      if (o < 8)       { g = xh  + (size_t)(m0 + row) * 2048 + k0 + cl; d = base + grp * 512; }
      else if (o < 16) { g = xl  + (size_t)(m0 + row) * 2048 + k0 + cl; d = base + 4096 + grp * 512; }
      else if (o < 32) { g = wth + (size_t)(n0 + row) * 2048 + k0 + cl; d = base + 8192 + grp * 512; }
      else             { g = wtl + (size_t)(n0 + row) * 2048 + k0 + cl; d = base + 16384 + grp * 512; }
      gll16(g, d);
    }
  };

  stage(0, 0);
  stage(1, 32);

  for (int ks = 0; ks < 64; ks++) {
    // counted wait: allow next tile's 6 loads to remain in flight; current tile's done.
    if (ks < 63) asm volatile("s_waitcnt vmcnt(6)" ::: "memory");
    else         asm volatile("s_waitcnt vmcnt(0)" ::: "memory");
    __builtin_amdgcn_s_barrier();
    if (ks + 2 < 64) stage((ks + 2) % 3, (ks + 2) * 32);
    const u16* lb = lds + (ks % 3) * 24576;

    short8 ah[4], al[4], bh[4], bl[4];
#pragma unroll
    for (int mf = 0; mf < 4; mf++) {
      int m = wm * 64 + mf * 16 + c16;
      int xo = m * 32 + ((rg ^ ((m >> 1) & 3)) * 8);
      ah[mf] = *(const short8*)(lb + xo);
      al[mf] = *(const short8*)(lb + 4096 + xo);
    }
#pragma unroll
    for (int nf = 0; nf < 4; nf++) {
      int n = wn * 64 + nf * 16 + c16;
      int xo = n * 32 + ((rg ^ ((n >> 1) & 3)) * 8);
      bh[nf] = *(const short8*)(lb + 8192 + xo);
      bl[nf] = *(const short8*)(lb + 16384 + xo);
    }
    __builtin_amdgcn_s_setprio(1);
#pragma unroll
    for (int mf = 0; mf < 4; mf++)
#pragma unroll
      for (int nf = 0; nf < 4; nf++) {
        acc[mf][nf] = __builtin_amdgcn_mfma_f32_16x16x32_bf16(ah[mf], bh[nf], acc[mf][nf], 0, 0, 0);
        acc[mf][nf] = __builtin_amdgcn_mfma_f32_16x16x32_bf16(ah[mf], bl[nf], acc[mf][nf], 0, 0, 0);
        acc[mf][nf] = __builtin_amdgcn_mfma_f32_16x16x32_bf16(al[mf], bh[nf], acc[mf][nf], 0, 0, 0);
      }
    __builtin_amdgcn_s_setprio(0);
  }
#pragma unroll
  for (int mf = 0; mf < 4; mf++)
#pragma unroll
    for (int nf = 0; nf < 4; nf++)
#pragma unroll
      for (int j = 0; j < 4; j++) {
        int m = m0 + wm * 64 + mf * 16 + rg * 4 + j;
        int n = n0 + wn * 64 + nf * 16 + c16;
        qkv[(size_t)m * QKVN + n] = acc[mf][nf][j];
      }
}

// ---------------- RoPE q -> f16 row-major (pre-scaled by log2e/sqrt(128)) ----------------
__global__ __launch_bounds__(256) void k_rope_q(const float* __restrict__ qkv,
                                                const float* __restrict__ cosb,
                                                const float* __restrict__ sinb,
                                                u16* __restrict__ qf) {
  int idx = blockIdx.x * 256 + threadIdx.x;  // SQ*16*64
  int i = idx & 63;
  int th = idx >> 6;
  int h = th & 15, t = th >> 4;
  float2 eo = *(const float2*)(qkv + (size_t)t * QKVN + h * 128 + 2 * i);
  float c = cosb[t * 64 + i], s = sinb[t * 64 + i];
  const float QSC = (float)(1.4426950408889634 * 0.08838834764831843);  // log2e/sqrt(128)
  float re = (eo.x * c - eo.y * s) * QSC;
  float ro = (eo.x * s + eo.y * c) * QSC;
  *(u32*)(qf + ((size_t)h * SQ + t) * 128 + 2 * i) = (u32)f2h(re) | ((u32)f2h(ro) << 16);
}

// ---------------- RoPE k -> FRAGMENT-MAJOR f16, output-major (coalesced 16B stores) ----------------
__global__ __launch_bounds__(256) void k_rope_kf(const float* __restrict__ qkv,
                                                 const float* __restrict__ cosb,
                                                 const float* __restrict__ sinb,
                                                 u16* __restrict__ kf2) {
  int hk = blockIdx.x & 7, tile = blockIdx.x >> 3;  // 512 blocks
  int tid = threadIdx.x;
  u16* dst = kf2 + (size_t)(hk * 64 + tile) * 8192;
#pragma unroll
  for (int rep = 0; rep < 4; rep++) {
    int p = rep * 256 + tid;          // [0,1024) output 16B words
    int f = p >> 6, lane = p & 63;
    int dk = f & 3, hf = (f >> 2) & 1, kk = f >> 3;
    int rg = lane >> 4, c16v = lane & 15;
    int t5 = ((c16v >> 2) << 3) | (hf << 2) | (c16v & 3);
    int t = tile * 64 + kk * 32 + t5;
    int d0 = dk * 32 + rg * 8;
    const float* src = qkv + (size_t)t * QKVN + 2048 + hk * 128 + d0;
    float4 a = *(const float4*)src;
    float4 b = *(const float4*)(src + 4);
    int i0 = d0 >> 1;
    float4 cs = *(const float4*)(cosb + t * 64 + i0);
    float4 sn = *(const float4*)(sinb + t * 64 + i0);
    float xe[4] = {a.x, a.z, b.x, b.z}, xo[4] = {a.y, a.w, b.y, b.w};
    float cc[4] = {cs.x, cs.y, cs.z, cs.w}, ss[4] = {sn.x, sn.y, sn.z, sn.w};
    u32 pk[4];
#pragma unroll
    for (int jj = 0; jj < 4; jj++) {
      float re = xe[jj] * cc[jj] - xo[jj] * ss[jj];
      float ro = xe[jj] * ss[jj] + xo[jj] * cc[jj];
      pk[jj] = (u32)f2h(re) | ((u32)f2h(ro) << 16);
    }
    *(uint4*)(dst + (size_t)p * 8) = make_uint4(pk[0], pk[1], pk[2], pk[3]);
  }
}

// ---------------- block means of roped k (double accumulation) ----------------
__global__ __launch_bounds__(64) void k_bm(const float* __restrict__ qkv,
                                           const float* __restrict__ cosb,
                                           const float* __restrict__ sinb,
                                           float* __restrict__ bm) {
  int hk = blockIdx.x >> 5, n = blockIdx.x & 31;
  int i = threadIdx.x;  // 64 pairs
  double se = 0.0, so = 0.0;
  for (int t = 0; t < 128; t++) {
    int tt = n * 128 + t;
    float2 eo = *(const float2*)(qkv + (size_t)tt * QKVN + 2048 + hk * 128 + 2 * i);
    float c = cosb[tt * 64 + i], s = sinb[tt * 64 + i];
    se += (double)(eo.x * c - eo.y * s);
    so += (double)(eo.x * s + eo.y * c);
  }
  float* o = bm + ((size_t)(hk * 32 + n)) * 128 + 2 * i;
  o[0] = (float)(se * (1.0 / 128.0));
  o[1] = (float)(so * (1.0 / 128.0));
}

// ---------------- gating: own-block in top-8? (only matters for b>=8) ----------------
__global__ __launch_bounds__(64) void k_gate(const float* __restrict__ qkv,
                                             const float* __restrict__ cosb,
                                             const float* __restrict__ sinb,
                                             const float* __restrict__ bm,
                                             unsigned char* __restrict__ sel) {
  __shared__ float q[64][129];
  __shared__ float bml[32 * 128];
  int bz = blockIdx.x;  // h*48 + (b-8)*2 + half
  int h = bz / 48;
  int rem = bz % 48;
  int b = 8 + (rem >> 1);
  int half = rem & 1;
  int tid = threadIdx.x;
  int hk = h >> 1;
  for (int rr = 0; rr < 64; rr++) {
    int ss = b * 128 + half * 64 + rr;
    float2 eo = *(const float2*)(qkv + (size_t)ss * QKVN + h * 128 + 2 * tid);
    float c = cosb[ss * 64 + tid], sn = sinb[ss * 64 + tid];
    q[rr][2 * tid]     = eo.x * c - eo.y * sn;
    q[rr][2 * tid + 1] = eo.x * sn + eo.y * c;
  }
  for (int o = tid; o < (b + 1) * 128; o += 64) bml[o] = bm[(size_t)hk * 32 * 128 + o];
  __syncthreads();
  int s = b * 128 + half * 64 + tid;
  double gb = 0.0;
  for (int d = 0; d < 128; d++) gb += (double)q[tid][d] * (double)bml[b * 128 + d];
  int cnt = 0;
  for (int n = 0; n < b; n++) {
    double g = 0.0;
    for (int d = 0; d < 128; d++) g += (double)q[tid][d] * (double)bml[n * 128 + d];
    cnt += (g >= gb) ? 1 : 0;
  }
  sel[h * SQ + s] = (cnt <= 7) ? 1 : 0;
}

// ---------------- v -> vt2 FRAGMENT-MAJOR f16 via padded-LDS transpose ----------------
__global__ __launch_bounds__(256) void k_vt2(const float* __restrict__ qkv, u16* __restrict__ vt2) {
  __shared__ float vb[64][129];
  int hk = blockIdx.x & 7, tile = blockIdx.x >> 3;  // 512 blocks
  int tid = threadIdx.x;
  int r4 = tid >> 6, cl = (tid & 63) * 2;
#pragma unroll
  for (int it = 0; it < 16; it++) {
    int row = it * 4 + r4;
    float2 v = *(const float2*)(qkv + (size_t)(tile * 64 + row) * QKVN + 3072 + hk * 128 + cl);
    vb[row][cl] = v.x;
    vb[row][cl + 1] = v.y;
  }
  __syncthreads();
  u16* dst = vt2 + (size_t)(hk * 64 + tile) * 8192;
#pragma unroll
  for (int rep = 0; rep < 4; rep++) {
    int p = rep * 256 + tid;          // [0,1024) output 16B words
    int g = p >> 6, lane = p & 63;
    int nf = g & 7, kk = g >> 3;
    int rg = lane >> 4, c16v = lane & 15;
    int d = nf * 16 + c16v;
    int tokb = kk * 32 + rg * 8;
    u32 pk[4];
#pragma unroll
    for (int jj = 0; jj < 4; jj++) {
      float v0 = vb[tokb + 2 * jj][d];
      float v1 = vb[tokb + 2 * jj + 1][d];
      pk[jj] = (u32)f2h(v0) | ((u32)f2h(v1) << 16);
    }
    *(uint4*)(dst + (size_t)p * 8) = make_uint4(pk[0], pk[1], pk[2], pk[3]);
  }
}

// ---------------- split-KV flash attention: KVBLK=32, fragment-major LDS dbuf (R5 measured) ----------------
__global__ __launch_bounds__(256) void k_attn_chunk(
    const u16* __restrict__ qf, const u16* __restrict__ kf2, const u16* __restrict__ vt2,
    const unsigned char* __restrict__ sel, u16* __restrict__ po, float* __restrict__ ml) {
  __shared__ u16 lds[2][8192];     // 2 bufs x (K 8KB | V 8KB) = 32KB
  const int L = blockIdx.x;        // [0,1280): laid out so XCD == hk
  const int hk = L & 7;
  const int c = L >> 3;            // [0,160)
  const int h = hk * 2 + (c & 1);
  const int cc = c >> 1;           // [0,80)
  int qb, chunk;
  if (cc < 8)       { qb = cc;                   chunk = 0; }
  else if (cc < 24) { qb = 8 + ((cc - 8) >> 1);  chunk = (cc - 8) & 1; }
  else if (cc < 48) { qb = 16 + (cc - 24) / 3;   chunk = (cc - 24) % 3; }
  else              { qb = 24 + ((cc - 48) >> 2); chunk = (cc - 48) & 3; }
  const int nt128 = (qb < 8) ? 8 : (qb + 1);
  const int t0 = chunk * 32;                       // 32-token units
  const int t1 = (t0 + 32 < nt128 * 4) ? t0 + 32 : nt128 * 4;
  const int tid = threadIdx.x;
  const int lane = tid & 63, wid = tid >> 6;
  const int rg = lane >> 4, c16 = lane & 15;
  const bool hasMask = (qb >= 8);

  half8 aq[2][4];
#pragma unroll
  for (int mi = 0; mi < 2; mi++)
#pragma unroll
    for (int dk = 0; dk < 4; dk++) {
      int srow = qb * 128 + wid * 32 + mi * 16 + c16;
      aq[mi][dk] = *(const half8*)(qf + ((size_t)h * SQ + srow) * 128 + dk * 32 + rg * 8);
    }

  bool os2[2] = {true, true};
  if (hasMask) {
#pragma unroll
    for (int mi = 0; mi < 2; mi++)
      os2[mi] = sel[h * SQ + qb * 128 + wid * 32 + mi * 16 + c16] != 0;
  }

  f32x4 accO[2][8];
#pragma unroll
  for (int mi = 0; mi < 2; mi++)
#pragma unroll
    for (int nf = 0; nf < 8; nf++) accO[mi][nf] = (f32x4){0.f, 0.f, 0.f, 0.f};
  float mrun[2] = {-1e30f, -1e30f}, lrun[2] = {0.f, 0.f};

  const u16* kbase = kf2 + (size_t)hk * 64 * 8192;   // 32-tile n at offset n*4096
  const u16* vbase = vt2 + (size_t)hk * 64 * 8192;

  auto stage = [&](int b, int n) {
    const u16* ks = kbase + (size_t)n * 4096;
    const u16* vs = vbase + (size_t)n * 4096;
#pragma unroll
    for (int r = 0; r < 2; r++) {
      gll16(ks + r * 2048 + wid * 512 + lane * 8, &lds[b][r * 2048 + wid * 512]);
      gll16(vs + r * 2048 + wid * 512 + lane * 8, &lds[b][4096 + r * 2048 + wid * 512]);
    }
  };

  stage(0, t0);

  for (int n = t0; n < t1; n++) {
    const int cur = (n - t0) & 1;
    __syncthreads();                 // staged tile ready, prev buf free
    if (n + 1 < t1) stage(cur ^ 1, n + 1);
    const u16* lb = &lds[cur][0];

    f32x4 st[2][2];                  // [hf][mi]
#pragma unroll
    for (int hf = 0; hf < 2; hf++)
#pragma unroll
      for (int mi = 0; mi < 2; mi++) st[hf][mi] = (f32x4){0.f, 0.f, 0.f, 0.f};

    __builtin_amdgcn_s_setprio(1);
#pragma unroll
    for (int hf = 0; hf < 2; hf++) {
      half8 ka[4];
#pragma unroll
      for (int dk = 0; dk < 4; dk++)
        ka[dk] = *(const half8*)(lb + (hf * 4 + dk) * 512 + lane * 8);
#pragma unroll
      for (int dk = 0; dk < 4; dk++) {
        st[hf][0] = __builtin_amdgcn_mfma_f32_16x16x32_f16(ka[dk], aq[0][dk], st[hf][0], 0, 0, 0);
        st[hf][1] = __builtin_amdgcn_mfma_f32_16x16x32_f16(ka[dk], aq[1][dk], st[hf][1], 0, 0, 0);
      }
    }
    __builtin_amdgcn_s_setprio(0);

    if (hasMask && n >= 4 * qb) {
#pragma unroll
      for (int mi = 0; mi < 2; mi++) {
        if (!os2[mi]) {
          int row = qb * 128 + wid * 32 + mi * 16 + c16;
#pragma unroll
          for (int hf = 0; hf < 2; hf++)
#pragma unroll
            for (int j = 0; j < 4; j++) {
              int tg = n * 32 + rg * 8 + hf * 4 + j;
              if (tg > row) st[hf][mi][j] = -1e30f;
            }
        }
      }
    }

#pragma unroll
    for (int mi = 0; mi < 2; mi++) {
      float mt = st[0][mi][0];
#pragma unroll
      for (int hf = 0; hf < 2; hf++)
#pragma unroll
        for (int j = 0; j < 4; j++)
          if (hf | j) mt = fmaxf(mt, st[hf][mi][j]);
      mt = fmaxf(mt, __shfl_xor(mt, 16, 64));
      mt = fmaxf(mt, __shfl_xor(mt, 32, 64));
      if (!__all(mt <= mrun[mi] + 8.f)) {
        float mnew = fmaxf(mrun[mi], mt);
        float sc = exp2f(mrun[mi] - mnew);
        mrun[mi] = mnew;
        lrun[mi] *= sc;
#pragma unroll
        for (int nf = 0; nf < 8; nf++) accO[mi][nf] *= sc;
      }
      float ps = 0.f;
#pragma unroll
      for (int hf = 0; hf < 2; hf++)
#pragma unroll
        for (int j = 0; j < 4; j++) {
          float p = exp2f(st[hf][mi][j] - mrun[mi]);
          st[hf][mi][j] = p;
          ps += p;
        }
      ps += __shfl_xor(ps, 16, 64);
      ps += __shfl_xor(ps, 32, 64);
      lrun[mi] += ps;
    }

    half8 pa[2];
#pragma unroll
    for (int mi = 0; mi < 2; mi++) {
      union { half8 v; _Float16 e[8]; } pu;
#pragma unroll
      for (int hf = 0; hf < 2; hf++)
#pragma unroll
        for (int j = 0; j < 4; j++)
          pu.e[hf * 4 + j] = (_Float16)st[hf][mi][j];
      pa[mi] = pu.v;
    }

    __builtin_amdgcn_s_setprio(1);
#pragma unroll
    for (int nf = 0; nf < 8; nf++) {
      half8 va = *(const half8*)(lb + 4096 + nf * 512 + lane * 8);
      accO[0][nf] = __builtin_amdgcn_mfma_f32_16x16x32_f16(va, pa[0], accO[0][nf], 0, 0, 0);
      accO[1][nf] = __builtin_amdgcn_mfma_f32_16x16x32_f16(va, pa[1], accO[1][nf], 0, 0, 0);
    }
    __builtin_amdgcn_s_setprio(0);
  }

  const int pidx = h * 80 + cidx(qb) + chunk;
  u16* pob = po + (size_t)pidx * 16384;
#pragma unroll
  for (int mi = 0; mi < 2; mi++) {
    float inv = 1.0f / lrun[mi];
    int row = wid * 32 + mi * 16 + c16;
#pragma unroll
    for (int nf = 0; nf < 8; nf++) {
      u32 p0 = (u32)f2h(accO[mi][nf][0] * inv) | ((u32)f2h(accO[mi][nf][1] * inv) << 16);
      u32 p1 = (u32)f2h(accO[mi][nf][2] * inv) | ((u32)f2h(accO[mi][nf][3] * inv) << 16);
      *(uint2*)&pob[row * 128 + nf * 16 + rg * 4] = make_uint2(p0, p1);
    }
    if (rg == 0)
      ml[(size_t)pidx * 128 + row] = mrun[mi] + log2f(lrun[mi]);
  }
}

// ---------------- combine split-KV partials -> attn (f16) ----------------
__global__ __launch_bounds__(256) void k_attn_combine(
    const u16* __restrict__ po, const float* __restrict__ ml, u16* __restrict__ attn) {
  const int qb = blockIdx.x, h = blockIdx.y;
  const int nc = (qb < 8) ? 1 : (qb < 16) ? 2 : (qb < 24) ? 3 : 4;
  const int base = h * 80 + cidx(qb);
  const int tid = threadIdx.x;
  const int r = tid >> 1, h64 = (tid & 1) * 64;
  float mp[4], M = -1e30f;
#pragma unroll
  for (int ci = 0; ci < 4; ci++) {
    mp[ci] = (ci < nc) ? ml[(size_t)(base + ci) * 128 + r] : -1e30f;
    M = fmaxf(M, mp[ci]);
  }
  float w[4], Ws = 0.f;
#pragma unroll
  for (int ci = 0; ci < 4; ci++) { w[ci] = exp2f(mp[ci] - M); Ws += (ci < nc) ? w[ci] : 0.f; }
  float inv = 1.0f / Ws;
  for (int d = 0; d < 64; d += 4) {
    float a[4] = {0.f, 0.f, 0.f, 0.f};
#pragma unroll
    for (int ci = 0; ci < 4; ci++) {
      if (ci < nc) {
        uint2 u = *(const uint2*)&po[(size_t)(base + ci) * 16384 + r * 128 + h64 + d];
        a[0] += w[ci] * h2f((u16)(u.x & 0xffff));
        a[1] += w[ci] * h2f((u16)(u.x >> 16));
        a[2] += w[ci] * h2f((u16)(u.y & 0xffff));
        a[3] += w[ci] * h2f((u16)(u.y >> 16));
      }
    }
    u32 p0 = (u32)f2h(a[0] * inv) | ((u32)f2h(a[1] * inv) << 16);
    u32 p1 = (u32)f2h(a[2] * inv) | ((u32)f2h(a[3] * inv) << 16);
    *(uint2*)&attn[(size_t)(qb * 128 + r) * DIMM + h * 128 + h64 + d] = make_uint2(p0, p1);
  }
}

// ---------------- out = attn @ wo (f16 GEMM, fp32 out, BK=64 2-phase, XCD-swizzled) ----------------
__global__ __launch_bounds__(256) void k_gemm_out(
    const u16* __restrict__ attn, const u16* __restrict__ wot, float* __restrict__ out) {
  __shared__ u16 lds[2 * 128 * 64];  // A | B, 32KB
  const int tid = threadIdx.x;
  const int lane = tid & 63, wid = tid >> 6;
  const int rg = lane >> 4, c16 = lane & 15;
  const int bid0 = blockIdx.y * 16 + blockIdx.x;           // 512 blocks
  const int swz = (bid0 & 7) * 64 + (bid0 >> 3);
  const int m0 = (swz >> 4) * 128, n0 = (swz & 15) * 128;
  const int wm = wid >> 1, wn = wid & 1;
  const u16* gsrc = (wid < 2) ? attn + (size_t)m0 * 2048 : wot + (size_t)n0 * 2048;
  const int sr = lane >> 3, scn = lane & 7;

  f32x4 acc[4][4];
#pragma unroll
  for (int a = 0; a < 4; a++)
#pragma unroll
    for (int b = 0; b < 4; b++) acc[a][b] = (f32x4){0.f, 0.f, 0.f, 0.f};

  for (int k0 = 0; k0 < 2048; k0 += 64) {
#pragma unroll
    for (int i = 0; i < 8; i++) {
      int slot = wid * 8 + i;
      int s2 = slot & 15;
      int r = s2 * 8 + sr;
      int cs = (scn ^ (r & 7)) * 8;
      gll16(gsrc + (size_t)r * 2048 + k0 + cs, lds + slot * 512);
    }
    __syncthreads();
#pragma unroll
    for (int kk = 0; kk < 2; kk++) {
      half8 a[4], b[4];
      int ch = kk * 4 + rg;
#pragma unroll
      for (int mf = 0; mf < 4; mf++) {
        int m = wm * 64 + mf * 16 + c16;
        a[mf] = *(const half8*)(lds + m * 64 + ((ch ^ (m & 7)) * 8));
      }
#pragma unroll
      for (int nf = 0; nf < 4; nf++) {
        int n = wn * 64 + nf * 16 + c16;
        b[nf] = *(const half8*)(lds + 8192 + n * 64 + ((ch ^ (n & 7)) * 8));
      }
#pragma unroll
      for (int mf = 0; mf < 4; mf++)
#pragma unroll
        for (int nf = 0; nf < 4; nf++)
          acc[mf][nf] = __builtin_amdgcn_mfma_f32_16x16x32_f16(a[mf], b[nf], acc[mf][nf], 0, 0, 0);
    }
    __syncthreads();
  }
#pragma unroll
  for (int mf = 0; mf < 4; mf++)
#pragma unroll
    for (int nf = 0; nf < 4; nf++)
#pragma unroll
      for (int j = 0; j < 4; j++) {
        int m = m0 + wm * 64 + mf * 16 + rg * 4 + j;
        int n = n0 + wn * 64 + nf * 16 + c16;
        out[(size_t)m * DIMM + n] = acc[mf][nf][j];
      }
}

extern "C" void kernel_launch(void* const* d_in, const int* in_sizes, int n_in,
                              void* d_out, int out_size, void* d_ws, size_t ws_size,
                              hipStream_t stream) {
  (void)in_sizes; (void)n_in; (void)out_size; (void)ws_size;
  const float* x  = (const float*)d_in[0];
  const float* wq = (const float*)d_in[1];
  const float* wk = (const float*)d_in[2];
  const float* wv = (const float*)d_in[3];
  const float* wo = (const float*)d_in[4];
  float* out = (float*)d_out;

  char* ws = (char*)d_ws;
  const size_t MB = 1024 * 1024;
  // Region A (128MB): xh|xl|wth|wtl|qkv during projection; aliased by po|ml for split-KV
  char* A = ws;
  u16*   xh  = (u16*)(A);
  u16*   xl  = (u16*)(A + 16 * MB);
  u16*   wth = (u16*)(A + 32 * MB);
  u16*   wtl = (u16*)(A + 48 * MB);
  float* qkv = (float*)(A + 64 * MB);
  u16*   po  = (u16*)(A);              // 40MB (1280 x 128 x 128 f16), overlays dead buffers
  float* ml  = (float*)(A + 48 * MB);  // 0.64MB, overlays dead wtl
  // Region B (persistent)
  char* B = ws + 128 * MB;
  size_t off = 0;
  auto alloc = [&](size_t b) { char* p = B + off; off += (b + 255) & ~(size_t)255; return p; };
  u16*   wot  = (u16*)alloc((size_t)DIMM * DIMM * 2);
  float* cosb = (float*)alloc((size_t)SQ * 64 * 4);
  float* sinb = (float*)alloc((size_t)SQ * 64 * 4);
  u16*   qf   = (u16*)alloc((size_t)16 * SQ * 128 * 2);
  u16*   kf2  = (u16*)alloc((size_t)8 * SQ * 128 * 2);
  u16*   vt2  = (u16*)alloc((size_t)8 * 128 * SQ * 2);
  float* bm   = (float*)alloc((size_t)8 * 32 * 128 * 4);
  unsigned char* sel = (unsigned char*)alloc((size_t)16 * SQ);
  u16*   attn = (u16*)alloc((size_t)SQ * DIMM * 2);

  const int QKV_LDS = 3 * 24576 * 2;  // 144KB
  hipFuncSetAttribute((const void*)k_gemm_qkv, hipFuncAttributeMaxDynamicSharedMemorySize, QKV_LDS);

  k_tables<<<SQ * 64 / 256, 256, 0, stream>>>(cosb, sinb);
  k_split_x<<<(SQ * DIMM) / (256 * 4), 256, 0, stream>>>(x, xh, xl);
  k_trans_split<<<dim3(32, 32), 256, 0, stream>>>(wq, 2048, wth, wtl, 0);
  k_trans_split<<<dim3(16, 32), 256, 0, stream>>>(wk, 1024, wth, wtl, 2048);
  k_trans_split<<<dim3(16, 32), 256, 0, stream>>>(wv, 1024, wth, wtl, 3072);
  k_trans_f16<<<dim3(32, 32), 256, 0, stream>>>(wo, 2048, wot);
  k_gemm_qkv<<<512, 512, QKV_LDS, stream>>>(xh, xl, wth, wtl, qkv);
  k_rope_q<<<(SQ * 16 * 64) / 256, 256, 0, stream>>>(qkv, cosb, sinb, qf);
  k_rope_kf<<<512, 256, 0, stream>>>(qkv, cosb, sinb, kf2);
  k_vt2<<<512, 256, 0, stream>>>(qkv, vt2);
  k_bm<<<256, 64, 0, stream>>>(qkv, cosb, sinb, bm);
  k_gate<<<16 * 48, 64, 0, stream>>>(qkv, cosb, sinb, bm, sel);
  // qkv (and xh/xl/wth/wtl) are dead past this point -> po/ml alias them
  k_attn_chunk<<<1280, 256, 0, stream>>>(qf, kf2, vt2, sel, po, ml);
  k_attn_combine<<<dim3(32, 16), 256, 0, stream>>>(po, ml, attn);
  k_gemm_out<<<dim3(16, 32), 256, 0, stream>>>(attn, wot, out);
}

// Round 10
// 564.845 us; speedup vs baseline: 1.0368x; 1.0368x over previous
//
#include <hip/hip_runtime.h>
#include <hip/hip_fp16.h>

#define SQ   4096
#define DIMM 2048
#define QKVN 4096   // 2048 q | 1024 k | 1024 v

typedef unsigned short u16;
typedef unsigned int u32;
typedef __attribute__((ext_vector_type(8))) short    short8;  // bf16x8 frag
typedef __attribute__((ext_vector_type(8))) _Float16 half8;   // f16x8 frag
typedef __attribute__((ext_vector_type(4))) float    f32x4;

__device__ __forceinline__ u16 f2bf(float f) {
  u32 u = __float_as_uint(f);
  u32 r = u + 0x7fffu + ((u >> 16) & 1u);
  return (u16)(r >> 16);
}
__device__ __forceinline__ float bf2f(u16 h) { return __uint_as_float(((u32)h) << 16); }
__device__ __forceinline__ u16 f2h(float f) { return __half_as_ushort(__float2half(f)); }
__device__ __forceinline__ float h2f(u16 h) { union { u16 u; _Float16 f; } c; c.u = h; return (float)c.f; }

__device__ __forceinline__ void gll16(const void* g, void* l) {
  __builtin_amdgcn_global_load_lds((const __attribute__((address_space(1))) void*)g,
                                   (__attribute__((address_space(3))) void*)l, 16, 0, 0);
}

// chunk-slot cumulative index per head: chunks of 8 KV blocks (128-token units)
__device__ __host__ __forceinline__ int cidx(int qb) {
  return qb < 8 ? qb : qb < 16 ? 8 + (qb - 8) * 2 : qb < 24 ? 24 + (qb - 16) * 3 : 48 + (qb - 24) * 4;
}

// ================= PREP PHASE 1 (fused): tables | split_x | W transposes =================
__global__ __launch_bounds__(256) void k_prep1(
    const float* __restrict__ x, const float* __restrict__ wq, const float* __restrict__ wk,
    const float* __restrict__ wv, const float* __restrict__ wo,
    float* __restrict__ cosb, float* __restrict__ sinb,
    u16* __restrict__ xh, u16* __restrict__ xl,
    u16* __restrict__ wth, u16* __restrict__ wtl, u16* __restrict__ wot) {
  __shared__ float t[64][65];
  const int b = blockIdx.x, tid = threadIdx.x;

  if (b < 1024) {                       // ---- RoPE tables ----
    int idx = b * 256 + tid;            // SQ*64
    int pos = idx >> 6, i = idx & 63;
    double f = 1.0 / pow(10000.0, (double)i / 64.0);
    float inv = (float)f;
    float ang = (float)pos * inv;
    cosb[idx] = (float)cos((double)ang);
    sinb[idx] = (float)sin((double)ang);
    return;
  }
  if (b < 9216) {                       // ---- split x into bf16 hi/lo ----
    size_t base = ((size_t)(b - 1024) * 256 + tid) * 4;
    float4 v = *(const float4*)(x + base);
    float vv[4] = {v.x, v.y, v.z, v.w};
    u16 hh[4], ll[4];
#pragma unroll
    for (int j = 0; j < 4; j++) {
      hh[j] = f2bf(vv[j]);
      ll[j] = f2bf(vv[j] - bf2f(hh[j]));
    }
    *(uint2*)(xh + base) = make_uint2((u32)hh[0] | ((u32)hh[1] << 16), (u32)hh[2] | ((u32)hh[3] << 16));
    *(uint2*)(xl + base) = make_uint2((u32)ll[0] | ((u32)ll[1] << 16), (u32)ll[2] | ((u32)ll[3] << 16));
    return;
  }
  // ---- weight transposes (shared-tile) ----
  const float* src; int N, rowOff, bx, by; bool f16only = false;
  if (b < 10240)      { int r = b - 9216;  src = wq; N = 2048; rowOff = 0;    bx = r & 31, by = r >> 5; }
  else if (b < 10752) { int r = b - 10240; src = wk; N = 1024; rowOff = 2048; bx = r & 15, by = r >> 4; }
  else if (b < 11264) { int r = b - 10752; src = wv; N = 1024; rowOff = 3072; bx = r & 15, by = r >> 4; }
  else                { int r = b - 11264; src = wo; N = 2048; rowOff = 0;    bx = r & 31, by = r >> 5; f16only = true; }
  int n0 = bx * 64, k0 = by * 64;
  int c = tid & 63, r4 = tid >> 6;
#pragma unroll
  for (int it = 0; it < 16; it++) {
    int kk = it * 4 + r4;
    t[kk][c] = src[(size_t)(k0 + kk) * N + n0 + c];
  }
  __syncthreads();
#pragma unroll
  for (int it = 0; it < 16; it++) {
    int nn = it * 4 + r4;
    float v = t[c][nn];
    size_t o = (size_t)(rowOff + n0 + nn) * 2048 + k0 + c;
    if (f16only) {
      wot[o] = f2h(v);
    } else {
      u16 hh = f2bf(v);
      wth[o] = hh;
      wtl[o] = f2bf(v - bf2f(hh));
    }
  }
}

// ---------------- QKV projection: bf16x3 split GEMM, 128x128 tile, BK=32 dbuf.
// XCD mapping: 4 m-tiles pinned per XCD (A panels L2-resident), n-major order. (R8 measured: 180us) ----
__global__ __launch_bounds__(256) void k_gemm_qkv(
    const u16* __restrict__ xh, const u16* __restrict__ xl,
    const u16* __restrict__ wth, const u16* __restrict__ wtl,
    float* __restrict__ qkv) {
  __shared__ u16 lds[2][16384];   // per buf: Ah|Al|Bh|Bl, each 128x32 u16 (4096), 32KB/buf
  const int tid = threadIdx.x;
  const int lane = tid & 63, wid = tid >> 6;
  const int rg = lane >> 4, c16 = lane & 15;
  const int bid0 = blockIdx.y * 32 + blockIdx.x;           // 1024 blocks
  const int xcd = bid0 & 7, local = bid0 >> 3;             // local in [0,128)
  const int m0 = (xcd * 4 + (local & 3)) * 128;            // m-tiles pinned per XCD
  const int n0 = (local >> 2) * 128;                       // n-major within XCD
  const int wm = wid >> 1, wn = wid & 1;
  const u16* gsrc = (wid == 0) ? xh + (size_t)m0 * 2048
                  : (wid == 1) ? xl + (size_t)m0 * 2048
                  : (wid == 2) ? wth + (size_t)n0 * 2048
                               : wtl + (size_t)n0 * 2048;
  const int srow4 = lane >> 2;   // 0..15
  const int pc = lane & 3;       // physical 16B chunk within 64B row

  f32x4 acc[4][4];
#pragma unroll
  for (int a = 0; a < 4; a++)
#pragma unroll
    for (int b = 0; b < 4; b++) acc[a][b] = (f32x4){0.f, 0.f, 0.f, 0.f};

  auto stage = [&](int b, int k0) {
#pragma unroll
    for (int i = 0; i < 8; i++) {
      int r = i * 16 + srow4;
      int cl = pc ^ ((r >> 1) & 3);
      gll16(gsrc + (size_t)r * 2048 + k0 + cl * 8, &lds[b][wid * 4096 + i * 512 + lane * 8]);
    }
  };

  stage(0, 0);

  for (int ks = 0; ks < 64; ks++) {
    __syncthreads();
    if (ks + 1 < 64) stage((ks & 1) ^ 1, (ks + 1) * 32);
    const u16* lb = lds[ks & 1];

    short8 ah[4], al[4], bh[4], bl[4];
#pragma unroll
    for (int mf = 0; mf < 4; mf++) {
      int m = wm * 64 + mf * 16 + c16;
      int xo = m * 32 + ((rg ^ ((m >> 1) & 3)) * 8);
      ah[mf] = *(const short8*)(lb + xo);
      al[mf] = *(const short8*)(lb + 4096 + xo);
    }
#pragma unroll
    for (int nf = 0; nf < 4; nf++) {
      int n = wn * 64 + nf * 16 + c16;
      int xo = n * 32 + ((rg ^ ((n >> 1) & 3)) * 8);
      bh[nf] = *(const short8*)(lb + 8192 + xo);
      bl[nf] = *(const short8*)(lb + 12288 + xo);
    }
    __builtin_amdgcn_s_setprio(1);
#pragma unroll
    for (int mf = 0; mf < 4; mf++)
#pragma unroll
      for (int nf = 0; nf < 4; nf++) {
        acc[mf][nf] = __builtin_amdgcn_mfma_f32_16x16x32_bf16(ah[mf], bh[nf], acc[mf][nf], 0, 0, 0);
        acc[mf][nf] = __builtin_amdgcn_mfma_f32_16x16x32_bf16(ah[mf], bl[nf], acc[mf][nf], 0, 0, 0);
        acc[mf][nf] = __builtin_amdgcn_mfma_f32_16x16x32_bf16(al[mf], bh[nf], acc[mf][nf], 0, 0, 0);
      }
    __builtin_amdgcn_s_setprio(0);
  }
#pragma unroll
  for (int mf = 0; mf < 4; mf++)
#pragma unroll
    for (int nf = 0; nf < 4; nf++)
#pragma unroll
      for (int j = 0; j < 4; j++) {
        int m = m0 + wm * 64 + mf * 16 + rg * 4 + j;
        int n = n0 + wn * 64 + nf * 16 + c16;
        qkv[(size_t)m * QKVN + n] = acc[mf][nf][j];
      }
}

// ================= PREP PHASE 2 (fused): rope_q | rope_kf | vt2 | bm =================
__global__ __launch_bounds__(256) void k_prep2(
    const float* __restrict__ qkv, const float* __restrict__ cosb, const float* __restrict__ sinb,
    u16* __restrict__ qf, u16* __restrict__ kf2, u16* __restrict__ vt2, float* __restrict__ bm) {
  __shared__ float vb[64][129];
  const int b = blockIdx.x, tid = threadIdx.x;

  if (b < 4096) {                       // ---- rope q (8 floats / thread) ----
    int p = b * 256 + tid;              // [0, SQ*2048/8)
    int t = p >> 8;
    int col8 = (p & 255) * 8;
    int h = col8 >> 7, d0 = col8 & 127;
    int i0 = d0 >> 1;
    const float* src = qkv + (size_t)t * QKVN + h * 128 + d0;
    float4 a = *(const float4*)src;
    float4 bq = *(const float4*)(src + 4);
    float4 cs = *(const float4*)(cosb + t * 64 + i0);
    float4 sn = *(const float4*)(sinb + t * 64 + i0);
    const float QSC = (float)(1.4426950408889634 * 0.08838834764831843);  // log2e/sqrt(128)
    float xe[4] = {a.x, a.z, bq.x, bq.z}, xo[4] = {a.y, a.w, bq.y, bq.w};
    float cc[4] = {cs.x, cs.y, cs.z, cs.w}, ss[4] = {sn.x, sn.y, sn.z, sn.w};
    u32 pk[4];
#pragma unroll
    for (int jj = 0; jj < 4; jj++) {
      float re = (xe[jj] * cc[jj] - xo[jj] * ss[jj]) * QSC;
      float ro = (xe[jj] * ss[jj] + xo[jj] * cc[jj]) * QSC;
      pk[jj] = (u32)f2h(re) | ((u32)f2h(ro) << 16);
    }
    *(uint4*)(qf + ((size_t)h * SQ + t) * 128 + d0) = make_uint4(pk[0], pk[1], pk[2], pk[3]);
    return;
  }
  if (b < 4608) {                       // ---- rope k -> fragment-major ----
    int r = b - 4096;
    int hk = r & 7, tile = r >> 3;
    u16* dst = kf2 + (size_t)(hk * 64 + tile) * 8192;
#pragma unroll
    for (int rep = 0; rep < 4; rep++) {
      int p = rep * 256 + tid;
      int f = p >> 6, lane = p & 63;
      int dk = f & 3, hf = (f >> 2) & 1, kk = f >> 3;
      int rg = lane >> 4, c16v = lane & 15;
      int t5 = ((c16v >> 2) << 3) | (hf << 2) | (c16v & 3);
      int t = tile * 64 + kk * 32 + t5;
      int d0 = dk * 32 + rg * 8;
      const float* src = qkv + (size_t)t * QKVN + 2048 + hk * 128 + d0;
      float4 a = *(const float4*)src;
      float4 bq = *(const float4*)(src + 4);
      int i0 = d0 >> 1;
      float4 cs = *(const float4*)(cosb + t * 64 + i0);
      float4 sn = *(const float4*)(sinb + t * 64 + i0);
      float xe[4] = {a.x, a.z, bq.x, bq.z}, xo[4] = {a.y, a.w, bq.y, bq.w};
      float cc[4] = {cs.x, cs.y, cs.z, cs.w}, ss[4] = {sn.x, sn.y, sn.z, sn.w};
      u32 pk[4];
#pragma unroll
      for (int jj = 0; jj < 4; jj++) {
        float re = xe[jj] * cc[jj] - xo[jj] * ss[jj];
        float ro = xe[jj] * ss[jj] + xo[jj] * cc[jj];
        pk[jj] = (u32)f2h(re) | ((u32)f2h(ro) << 16);
      }
      *(uint4*)(dst + (size_t)p * 8) = make_uint4(pk[0], pk[1], pk[2], pk[3]);
    }
    return;
  }
  if (b < 5120) {                       // ---- v -> fragment-major via padded-LDS transpose ----
    int r = b - 4608;
    int hk = r & 7, tile = r >> 3;
    int r4 = tid >> 6, cl = (tid & 63) * 2;
#pragma unroll
    for (int it = 0; it < 16; it++) {
      int row = it * 4 + r4;
      float2 v = *(const float2*)(qkv + (size_t)(tile * 64 + row) * QKVN + 3072 + hk * 128 + cl);
      vb[row][cl] = v.x;
      vb[row][cl + 1] = v.y;
    }
    __syncthreads();
    u16* dst = vt2 + (size_t)(hk * 64 + tile) * 8192;
#pragma unroll
    for (int rep = 0; rep < 4; rep++) {
      int p = rep * 256 + tid;
      int g = p >> 6, lane = p & 63;
      int nf = g & 7, kk = g >> 3;
      int rg = lane >> 4, c16v = lane & 15;
      int d = nf * 16 + c16v;
      int tokb = kk * 32 + rg * 8;
      u32 pk[4];
#pragma unroll
      for (int jj = 0; jj < 4; jj++) {
        float v0 = vb[tokb + 2 * jj][d];
        float v1 = vb[tokb + 2 * jj + 1][d];
        pk[jj] = (u32)f2h(v0) | ((u32)f2h(v1) << 16);
      }
      *(uint4*)(dst + (size_t)p * 8) = make_uint4(pk[0], pk[1], pk[2], pk[3]);
    }
    return;
  }
  {                                     // ---- block means (4 units per block, 1 per wave) ----
    int u = (b - 5120) * 4 + (tid >> 6);
    int hk = u >> 5, n = u & 31;
    int i = tid & 63;
    double se = 0.0, so = 0.0;
    for (int t = 0; t < 128; t++) {
      int tt = n * 128 + t;
      float2 eo = *(const float2*)(qkv + (size_t)tt * QKVN + 2048 + hk * 128 + 2 * i);
      float c = cosb[tt * 64 + i], s = sinb[tt * 64 + i];
      se += (double)(eo.x * c - eo.y * s);
      so += (double)(eo.x * s + eo.y * c);
    }
    float* o = bm + ((size_t)(hk * 32 + n)) * 128 + 2 * i;
    o[0] = (float)(se * (1.0 / 128.0));
    o[1] = (float)(so * (1.0 / 128.0));
  }
}

// ---------------- gating: own-block in top-8? (only matters for b>=8) ----------------
__global__ __launch_bounds__(64) void k_gate(const float* __restrict__ qkv,
                                             const float* __restrict__ cosb,
                                             const float* __restrict__ sinb,
                                             const float* __restrict__ bm,
                                             unsigned char* __restrict__ sel) {
  __shared__ float q[64][129];
  __shared__ float bml[32 * 128];
  int bz = blockIdx.x;  // h*48 + (b-8)*2 + half
  int h = bz / 48;
  int rem = bz % 48;
  int b = 8 + (rem >> 1);
  int half = rem & 1;
  int tid = threadIdx.x;
  int hk = h >> 1;
  for (int rr = 0; rr < 64; rr++) {
    int ss = b * 128 + half * 64 + rr;
    float2 eo = *(const float2*)(qkv + (size_t)ss * QKVN + h * 128 + 2 * tid);
    float c = cosb[ss * 64 + tid], sn = sinb[ss * 64 + tid];
    q[rr][2 * tid]     = eo.x * c - eo.y * sn;
    q[rr][2 * tid + 1] = eo.x * sn + eo.y * c;
  }
  for (int o = tid; o < (b + 1) * 128; o += 64) bml[o] = bm[(size_t)hk * 32 * 128 + o];
  __syncthreads();
  int s = b * 128 + half * 64 + tid;
  double gb = 0.0;
  for (int d = 0; d < 128; d++) gb += (double)q[tid][d] * (double)bml[b * 128 + d];
  int cnt = 0;
  for (int n = 0; n < b; n++) {
    double g = 0.0;
    for (int d = 0; d < 128; d++) g += (double)q[tid][d] * (double)bml[n * 128 + d];
    cnt += (g >= gb) ? 1 : 0;
  }
  sel[h * SQ + s] = (cnt <= 7) ? 1 : 0;
}

// ---------------- split-KV flash attention: KVBLK=32, fragment-major LDS dbuf (R5 measured) ----------------
__global__ __launch_bounds__(256) void k_attn_chunk(
    const u16* __restrict__ qf, const u16* __restrict__ kf2, const u16* __restrict__ vt2,
    const unsigned char* __restrict__ sel, u16* __restrict__ po, float* __restrict__ ml) {
  __shared__ u16 lds[2][8192];     // 2 bufs x (K 8KB | V 8KB) = 32KB
  const int L = blockIdx.x;        // [0,1280): laid out so XCD == hk
  const int hk = L & 7;
  const int c = L >> 3;            // [0,160)
  const int h = hk * 2 + (c & 1);
  const int cc = c >> 1;           // [0,80)
  int qb, chunk;
  if (cc < 8)       { qb = cc;                   chunk = 0; }
  else if (cc < 24) { qb = 8 + ((cc - 8) >> 1);  chunk = (cc - 8) & 1; }
  else if (cc < 48) { qb = 16 + (cc - 24) / 3;   chunk = (cc - 24) % 3; }
  else              { qb = 24 + ((cc - 48) >> 2); chunk = (cc - 48) & 3; }
  const int nt128 = (qb < 8) ? 8 : (qb + 1);
  const int t0 = chunk * 32;                       // 32-token units
  const int t1 = (t0 + 32 < nt128 * 4) ? t0 + 32 : nt128 * 4;
  const int tid = threadIdx.x;
  const int lane = tid & 63, wid = tid >> 6;
  const int rg = lane >> 4, c16 = lane & 15;
  const bool hasMask = (qb >= 8);

  half8 aq[2][4];
#pragma unroll
  for (int mi = 0; mi < 2; mi++)
#pragma unroll
    for (int dk = 0; dk < 4; dk++) {
      int srow = qb * 128 + wid * 32 + mi * 16 + c16;
      aq[mi][dk] = *(const half8*)(qf + ((size_t)h * SQ + srow) * 128 + dk * 32 + rg * 8);
    }

  bool os2[2] = {true, true};
  if (hasMask) {
#pragma unroll
    for (int mi = 0; mi < 2; mi++)
      os2[mi] = sel[h * SQ + qb * 128 + wid * 32 + mi * 16 + c16] != 0;
  }

  f32x4 accO[2][8];
#pragma unroll
  for (int mi = 0; mi < 2; mi++)
#pragma unroll
    for (int nf = 0; nf < 8; nf++) accO[mi][nf] = (f32x4){0.f, 0.f, 0.f, 0.f};
  float mrun[2] = {-1e30f, -1e30f}, lrun[2] = {0.f, 0.f};

  const u16* kbase = kf2 + (size_t)hk * 64 * 8192;   // 32-tile n at offset n*4096
  const u16* vbase = vt2 + (size_t)hk * 64 * 8192;

  auto stage = [&](int b, int n) {
    const u16* ks = kbase + (size_t)n * 4096;
    const u16* vs = vbase + (size_t)n * 4096;
#pragma unroll
    for (int r = 0; r < 2; r++) {
      gll16(ks + r * 2048 + wid * 512 + lane * 8, &lds[b][r * 2048 + wid * 512]);
      gll16(vs + r * 2048 + wid * 512 + lane * 8, &lds[b][4096 + r * 2048 + wid * 512]);
    }
  };

  stage(0, t0);

  for (int n = t0; n < t1; n++) {
    const int cur = (n - t0) & 1;
    __syncthreads();
    if (n + 1 < t1) stage(cur ^ 1, n + 1);
    const u16* lb = &lds[cur][0];

    f32x4 st[2][2];                  // [hf][mi]
#pragma unroll
    for (int hf = 0; hf < 2; hf++)
#pragma unroll
      for (int mi = 0; mi < 2; mi++) st[hf][mi] = (f32x4){0.f, 0.f, 0.f, 0.f};

    __builtin_amdgcn_s_setprio(1);
#pragma unroll
    for (int hf = 0; hf < 2; hf++) {
      half8 ka[4];
#pragma unroll
      for (int dk = 0; dk < 4; dk++)
        ka[dk] = *(const half8*)(lb + (hf * 4 + dk) * 512 + lane * 8);
#pragma unroll
      for (int dk = 0; dk < 4; dk++) {
        st[hf][0] = __builtin_amdgcn_mfma_f32_16x16x32_f16(ka[dk], aq[0][dk], st[hf][0], 0, 0, 0);
        st[hf][1] = __builtin_amdgcn_mfma_f32_16x16x32_f16(ka[dk], aq[1][dk], st[hf][1], 0, 0, 0);
      }
    }
    __builtin_amdgcn_s_setprio(0);

    if (hasMask && n >= 4 * qb) {
#pragma unroll
      for (int mi = 0; mi < 2; mi++) {
        if (!os2[mi]) {
          int row = qb * 128 + wid * 32 + mi * 16 + c16;
#pragma unroll
          for (int hf = 0; hf < 2; hf++)
#pragma unroll
            for (int j = 0; j < 4; j++) {
              int tg = n * 32 + rg * 8 + hf * 4 + j;
              if (tg > row) st[hf][mi][j] = -1e30f;
            }
        }
      }
    }

#pragma unroll
    for (int mi = 0; mi < 2; mi++) {
      float mt = st[0][mi][0];
#pragma unroll
      for (int hf = 0; hf < 2; hf++)
#pragma unroll
        for (int j = 0; j < 4; j++)
          if (hf | j) mt = fmaxf(mt, st[hf][mi][j]);
      mt = fmaxf(mt, __shfl_xor(mt, 16, 64));
      mt = fmaxf(mt, __shfl_xor(mt, 32, 64));
      if (!__all(mt <= mrun[mi] + 8.f)) {
        float mnew = fmaxf(mrun[mi], mt);
        float sc = exp2f(mrun[mi] - mnew);
        mrun[mi] = mnew;
        lrun[mi] *= sc;
#pragma unroll
        for (int nf = 0; nf < 8; nf++) accO[mi][nf] *= sc;
      }
      float ps = 0.f;
#pragma unroll
      for (int hf = 0; hf < 2; hf++)
#pragma unroll
        for (int j = 0; j < 4; j++) {
          float p = exp2f(st[hf][mi][j] - mrun[mi]);
          st[hf][mi][j] = p;
          ps += p;
        }
      ps += __shfl_xor(ps, 16, 64);
      ps += __shfl_xor(ps, 32, 64);
      lrun[mi] += ps;
    }

    half8 pa[2];
#pragma unroll
    for (int mi = 0; mi < 2; mi++) {
      union { half8 v; _Float16 e[8]; } pu;
#pragma unroll
      for (int hf = 0; hf < 2; hf++)
#pragma unroll
        for (int j = 0; j < 4; j++)
          pu.e[hf * 4 + j] = (_Float16)st[hf][mi][j];
      pa[mi] = pu.v;
    }

    __builtin_amdgcn_s_setprio(1);
#pragma unroll
    for (int nf = 0; nf < 8; nf++) {
      half8 va = *(const half8*)(lb + 4096 + nf * 512 + lane * 8);
      accO[0][nf] = __builtin_amdgcn_mfma_f32_16x16x32_f16(va, pa[0], accO[0][nf], 0, 0, 0);
      accO[1][nf] = __builtin_amdgcn_mfma_f32_16x16x32_f16(va, pa[1], accO[1][nf], 0, 0, 0);
    }
    __builtin_amdgcn_s_setprio(0);
  }

  const int pidx = h * 80 + cidx(qb) + chunk;
  u16* pob = po + (size_t)pidx * 16384;
#pragma unroll
  for (int mi = 0; mi < 2; mi++) {
    float inv = 1.0f / lrun[mi];
    int row = wid * 32 + mi * 16 + c16;
#pragma unroll
    for (int nf = 0; nf < 8; nf++) {
      u32 p0 = (u32)f2h(accO[mi][nf][0] * inv) | ((u32)f2h(accO[mi][nf][1] * inv) << 16);
      u32 p1 = (u32)f2h(accO[mi][nf][2] * inv) | ((u32)f2h(accO[mi][nf][3] * inv) << 16);
      *(uint2*)&pob[row * 128 + nf * 16 + rg * 4] = make_uint2(p0, p1);
    }
    if (rg == 0)
      ml[(size_t)pidx * 128 + row] = mrun[mi] + log2f(lrun[mi]);
  }
}

// ---------------- combine split-KV partials -> attn (f16) ----------------
__global__ __launch_bounds__(256) void k_attn_combine(
    const u16* __restrict__ po, const float* __restrict__ ml, u16* __restrict__ attn) {
  const int qb = blockIdx.x, h = blockIdx.y;
  const int nc = (qb < 8) ? 1 : (qb < 16) ? 2 : (qb < 24) ? 3 : 4;
  const int base = h * 80 + cidx(qb);
  const int tid = threadIdx.x;
  const int r = tid >> 1, h64 = (tid & 1) * 64;
  float mp[4], M = -1e30f;
#pragma unroll
  for (int ci = 0; ci < 4; ci++) {
    mp[ci] = (ci < nc) ? ml[(size_t)(base + ci) * 128 + r] : -1e30f;
    M = fmaxf(M, mp[ci]);
  }
  float w[4], Ws = 0.f;
#pragma unroll
  for (int ci = 0; ci < 4; ci++) { w[ci] = exp2f(mp[ci] - M); Ws += (ci < nc) ? w[ci] : 0.f; }
  float inv = 1.0f / Ws;
  for (int d = 0; d < 64; d += 4) {
    float a[4] = {0.f, 0.f, 0.f, 0.f};
#pragma unroll
    for (int ci = 0; ci < 4; ci++) {
      if (ci < nc) {
        uint2 u = *(const uint2*)&po[(size_t)(base + ci) * 16384 + r * 128 + h64 + d];
        a[0] += w[ci] * h2f((u16)(u.x & 0xffff));
        a[1] += w[ci] * h2f((u16)(u.x >> 16));
        a[2] += w[ci] * h2f((u16)(u.y & 0xffff));
        a[3] += w[ci] * h2f((u16)(u.y >> 16));
      }
    }
    u32 p0 = (u32)f2h(a[0] * inv) | ((u32)f2h(a[1] * inv) << 16);
    u32 p1 = (u32)f2h(a[2] * inv) | ((u32)f2h(a[3] * inv) << 16);
    *(uint2*)&attn[(size_t)(qb * 128 + r) * DIMM + h * 128 + h64 + d] = make_uint2(p0, p1);
  }
}

// ---------------- out = attn @ wo (f16 GEMM, fp32 out, BK=64 2-phase, XCD-swizzled) ----------------
__global__ __launch_bounds__(256) void k_gemm_out(
    const u16* __restrict__ attn, const u16* __restrict__ wot, float* __restrict__ out) {
  __shared__ u16 lds[2 * 128 * 64];  // A | B, 32KB
  const int tid = threadIdx.x;
  const int lane = tid & 63, wid = tid >> 6;
  const int rg = lane >> 4, c16 = lane & 15;
  const int bid0 = blockIdx.y * 16 + blockIdx.x;           // 512 blocks
  const int swz = (bid0 & 7) * 64 + (bid0 >> 3);
  const int m0 = (swz >> 4) * 128, n0 = (swz & 15) * 128;
  const int wm = wid >> 1, wn = wid & 1;
  const u16* gsrc = (wid < 2) ? attn + (size_t)m0 * 2048 : wot + (size_t)n0 * 2048;
  const int sr = lane >> 3, scn = lane & 7;

  f32x4 acc[4][4];
#pragma unroll
  for (int a = 0; a < 4; a++)
#pragma unroll
    for (int b = 0; b < 4; b++) acc[a][b] = (f32x4){0.f, 0.f, 0.f, 0.f};

  for (int k0 = 0; k0 < 2048; k0 += 64) {
#pragma unroll
    for (int i = 0; i < 8; i++) {
      int slot = wid * 8 + i;
      int s2 = slot & 15;
      int r = s2 * 8 + sr;
      int cs = (scn ^ (r & 7)) * 8;
      gll16(gsrc + (size_t)r * 2048 + k0 + cs, lds + slot * 512);
    }
    __syncthreads();
#pragma unroll
    for (int kk = 0; kk < 2; kk++) {
      half8 a[4], b[4];
      int ch = kk * 4 + rg;
#pragma unroll
      for (int mf = 0; mf < 4; mf++) {
        int m = wm * 64 + mf * 16 + c16;
        a[mf] = *(const half8*)(lds + m * 64 + ((ch ^ (m & 7)) * 8));
      }
#pragma unroll
      for (int nf = 0; nf < 4; nf++) {
        int n = wn * 64 + nf * 16 + c16;
        b[nf] = *(const half8*)(lds + 8192 + n * 64 + ((ch ^ (n & 7)) * 8));
      }
#pragma unroll
      for (int mf = 0; mf < 4; mf++)
#pragma unroll
        for (int nf = 0; nf < 4; nf++)
          acc[mf][nf] = __builtin_amdgcn_mfma_f32_16x16x32_f16(a[mf], b[nf], acc[mf][nf], 0, 0, 0);
    }
    __syncthreads();
  }
#pragma unroll
  for (int mf = 0; mf < 4; mf++)
#pragma unroll
    for (int nf = 0; nf < 4; nf++)
#pragma unroll
      for (int j = 0; j < 4; j++) {
        int m = m0 + wm * 64 + mf * 16 + rg * 4 + j;
        int n = n0 + wn * 64 + nf * 16 + c16;
        out[(size_t)m * DIMM + n] = acc[mf][nf][j];
      }
}

extern "C" void kernel_launch(void* const* d_in, const int* in_sizes, int n_in,
                              void* d_out, int out_size, void* d_ws, size_t ws_size,
                              hipStream_t stream) {
  (void)in_sizes; (void)n_in; (void)out_size; (void)ws_size;
  const float* x  = (const float*)d_in[0];
  const float* wq = (const float*)d_in[1];
  const float* wk = (const float*)d_in[2];
  const float* wv = (const float*)d_in[3];
  const float* wo = (const float*)d_in[4];
  float* out = (float*)d_out;

  char* ws = (char*)d_ws;
  const size_t MB = 1024 * 1024;
  // Region A (128MB): xh|xl|wth|wtl|qkv during projection; aliased by po|ml for split-KV
  char* A = ws;
  u16*   xh  = (u16*)(A);
  u16*   xl  = (u16*)(A + 16 * MB);
  u16*   wth = (u16*)(A + 32 * MB);
  u16*   wtl = (u16*)(A + 48 * MB);
  float* qkv = (float*)(A + 64 * MB);
  u16*   po  = (u16*)(A);              // 40MB (1280 x 128 x 128 f16), overlays dead buffers
  float* ml  = (float*)(A + 48 * MB);  // 0.64MB, overlays dead wtl
  // Region B (persistent)
  char* B = ws + 128 * MB;
  size_t off = 0;
  auto alloc = [&](size_t b) { char* p = B + off; off += (b + 255) & ~(size_t)255; return p; };
  u16*   wot  = (u16*)alloc((size_t)DIMM * DIMM * 2);
  float* cosb = (float*)alloc((size_t)SQ * 64 * 4);
  float* sinb = (float*)alloc((size_t)SQ * 64 * 4);
  u16*   qf   = (u16*)alloc((size_t)16 * SQ * 128 * 2);
  u16*   kf2  = (u16*)alloc((size_t)8 * SQ * 128 * 2);
  u16*   vt2  = (u16*)alloc((size_t)8 * 128 * SQ * 2);
  float* bm   = (float*)alloc((size_t)8 * 32 * 128 * 4);
  unsigned char* sel = (unsigned char*)alloc((size_t)16 * SQ);
  u16*   attn = (u16*)alloc((size_t)SQ * DIMM * 2);

  k_prep1<<<12288, 256, 0, stream>>>(x, wq, wk, wv, wo, cosb, sinb, xh, xl, wth, wtl, wot);
  k_gemm_qkv<<<dim3(32, 32), 256, 0, stream>>>(xh, xl, wth, wtl, qkv);
  k_prep2<<<5184, 256, 0, stream>>>(qkv, cosb, sinb, qf, kf2, vt2, bm);
  k_gate<<<16 * 48, 64, 0, stream>>>(qkv, cosb, sinb, bm, sel);
  // qkv (and xh/xl/wth/wtl) are dead past this point -> po/ml alias them
  k_attn_chunk<<<1280, 256, 0, stream>>>(qf, kf2, vt2, sel, po, ml);
  k_attn_combine<<<dim3(32, 16), 256, 0, stream>>>(po, ml, attn);
  k_gemm_out<<<dim3(16, 32), 256, 0, stream>>>(attn, wot, out);
}

// Round 11
// 558.075 us; speedup vs baseline: 1.0493x; 1.0121x over previous
//
#include <hip/hip_runtime.h>
#include <hip/hip_fp16.h>

#define SQ   4096
#define DIMM 2048
#define QKVN 4096   // 2048 q | 1024 k | 1024 v

typedef unsigned short u16;
typedef unsigned int u32;
typedef __attribute__((ext_vector_type(8))) short    short8;  // bf16x8 frag
typedef __attribute__((ext_vector_type(8))) _Float16 half8;   // f16x8 frag
typedef __attribute__((ext_vector_type(4))) float    f32x4;

__device__ __forceinline__ u16 f2bf(float f) {
  u32 u = __float_as_uint(f);
  u32 r = u + 0x7fffu + ((u >> 16) & 1u);
  return (u16)(r >> 16);
}
__device__ __forceinline__ float bf2f(u16 h) { return __uint_as_float(((u32)h) << 16); }
__device__ __forceinline__ u16 f2h(float f) { return __half_as_ushort(__float2half(f)); }
__device__ __forceinline__ float h2f(u16 h) { union { u16 u; _Float16 f; } c; c.u = h; return (float)c.f; }

__device__ __forceinline__ void gll16(const void* g, void* l) {
  __builtin_amdgcn_global_load_lds((const __attribute__((address_space(1))) void*)g,
                                   (__attribute__((address_space(3))) void*)l, 16, 0, 0);
}

// chunk-slot cumulative index per head: chunks of 8 KV blocks (128-token units)
__device__ __host__ __forceinline__ int cidx(int qb) {
  return qb < 8 ? qb : qb < 16 ? 8 + (qb - 8) * 2 : qb < 24 ? 24 + (qb - 16) * 3 : 48 + (qb - 24) * 4;
}

// ================= PREP PHASE 1 (fused): tables | split_x | W transposes =================
__global__ __launch_bounds__(256) void k_prep1(
    const float* __restrict__ x, const float* __restrict__ wq, const float* __restrict__ wk,
    const float* __restrict__ wv, const float* __restrict__ wo,
    float* __restrict__ cosb, float* __restrict__ sinb,
    u16* __restrict__ xh, u16* __restrict__ xl,
    u16* __restrict__ wth, u16* __restrict__ wtl, u16* __restrict__ wot) {
  __shared__ float t[64][65];
  const int b = blockIdx.x, tid = threadIdx.x;

  if (b < 1024) {                       // ---- RoPE tables ----
    int idx = b * 256 + tid;            // SQ*64
    int pos = idx >> 6, i = idx & 63;
    double f = 1.0 / pow(10000.0, (double)i / 64.0);
    float inv = (float)f;
    float ang = (float)pos * inv;
    cosb[idx] = (float)cos((double)ang);
    sinb[idx] = (float)sin((double)ang);
    return;
  }
  if (b < 9216) {                       // ---- split x into bf16 hi/lo ----
    size_t base = ((size_t)(b - 1024) * 256 + tid) * 4;
    float4 v = *(const float4*)(x + base);
    float vv[4] = {v.x, v.y, v.z, v.w};
    u16 hh[4], ll[4];
#pragma unroll
    for (int j = 0; j < 4; j++) {
      hh[j] = f2bf(vv[j]);
      ll[j] = f2bf(vv[j] - bf2f(hh[j]));
    }
    *(uint2*)(xh + base) = make_uint2((u32)hh[0] | ((u32)hh[1] << 16), (u32)hh[2] | ((u32)hh[3] << 16));
    *(uint2*)(xl + base) = make_uint2((u32)ll[0] | ((u32)ll[1] << 16), (u32)ll[2] | ((u32)ll[3] << 16));
    return;
  }
  // ---- weight transposes (shared-tile) ----
  const float* src; int N, rowOff, bx, by; bool f16only = false;
  if (b < 10240)      { int r = b - 9216;  src = wq; N = 2048; rowOff = 0;    bx = r & 31, by = r >> 5; }
  else if (b < 10752) { int r = b - 10240; src = wk; N = 1024; rowOff = 2048; bx = r & 15, by = r >> 4; }
  else if (b < 11264) { int r = b - 10752; src = wv; N = 1024; rowOff = 3072; bx = r & 15, by = r >> 4; }
  else                { int r = b - 11264; src = wo; N = 2048; rowOff = 0;    bx = r & 31, by = r >> 5; f16only = true; }
  int n0 = bx * 64, k0 = by * 64;
  int c = tid & 63, r4 = tid >> 6;
#pragma unroll
  for (int it = 0; it < 16; it++) {
    int kk = it * 4 + r4;
    t[kk][c] = src[(size_t)(k0 + kk) * N + n0 + c];
  }
  __syncthreads();
#pragma unroll
  for (int it = 0; it < 16; it++) {
    int nn = it * 4 + r4;
    float v = t[c][nn];
    size_t o = (size_t)(rowOff + n0 + nn) * 2048 + k0 + c;
    if (f16only) {
      wot[o] = f2h(v);
    } else {
      u16 hh = f2bf(v);
      wth[o] = hh;
      wtl[o] = f2bf(v - bf2f(hh));
    }
  }
}

// ---------------- QKV projection: bf16x3 split GEMM, 128x128 tile, BK=32 dbuf.
// XCD mapping: 4 m-tiles pinned per XCD (A panels L2-resident), n-major order. (R8 measured: 180us) ----
__global__ __launch_bounds__(256) void k_gemm_qkv(
    const u16* __restrict__ xh, const u16* __restrict__ xl,
    const u16* __restrict__ wth, const u16* __restrict__ wtl,
    float* __restrict__ qkv) {
  __shared__ u16 lds[2][16384];   // per buf: Ah|Al|Bh|Bl, each 128x32 u16 (4096), 32KB/buf
  const int tid = threadIdx.x;
  const int lane = tid & 63, wid = tid >> 6;
  const int rg = lane >> 4, c16 = lane & 15;
  const int bid0 = blockIdx.y * 32 + blockIdx.x;           // 1024 blocks
  const int xcd = bid0 & 7, local = bid0 >> 3;             // local in [0,128)
  const int m0 = (xcd * 4 + (local & 3)) * 128;            // m-tiles pinned per XCD
  const int n0 = (local >> 2) * 128;                       // n-major within XCD
  const int wm = wid >> 1, wn = wid & 1;
  const u16* gsrc = (wid == 0) ? xh + (size_t)m0 * 2048
                  : (wid == 1) ? xl + (size_t)m0 * 2048
                  : (wid == 2) ? wth + (size_t)n0 * 2048
                               : wtl + (size_t)n0 * 2048;
  const int srow4 = lane >> 2;   // 0..15
  const int pc = lane & 3;       // physical 16B chunk within 64B row

  f32x4 acc[4][4];
#pragma unroll
  for (int a = 0; a < 4; a++)
#pragma unroll
    for (int b = 0; b < 4; b++) acc[a][b] = (f32x4){0.f, 0.f, 0.f, 0.f};

  auto stage = [&](int b, int k0) {
#pragma unroll
    for (int i = 0; i < 8; i++) {
      int r = i * 16 + srow4;
      int cl = pc ^ ((r >> 1) & 3);
      gll16(gsrc + (size_t)r * 2048 + k0 + cl * 8, &lds[b][wid * 4096 + i * 512 + lane * 8]);
    }
  };

  stage(0, 0);

  for (int ks = 0; ks < 64; ks++) {
    __syncthreads();
    if (ks + 1 < 64) stage((ks & 1) ^ 1, (ks + 1) * 32);
    const u16* lb = lds[ks & 1];

    short8 ah[4], al[4], bh[4], bl[4];
#pragma unroll
    for (int mf = 0; mf < 4; mf++) {
      int m = wm * 64 + mf * 16 + c16;
      int xo = m * 32 + ((rg ^ ((m >> 1) & 3)) * 8);
      ah[mf] = *(const short8*)(lb + xo);
      al[mf] = *(const short8*)(lb + 4096 + xo);
    }
#pragma unroll
    for (int nf = 0; nf < 4; nf++) {
      int n = wn * 64 + nf * 16 + c16;
      int xo = n * 32 + ((rg ^ ((n >> 1) & 3)) * 8);
      bh[nf] = *(const short8*)(lb + 8192 + xo);
      bl[nf] = *(const short8*)(lb + 12288 + xo);
    }
    __builtin_amdgcn_s_setprio(1);
#pragma unroll
    for (int mf = 0; mf < 4; mf++)
#pragma unroll
      for (int nf = 0; nf < 4; nf++) {
        acc[mf][nf] = __builtin_amdgcn_mfma_f32_16x16x32_bf16(ah[mf], bh[nf], acc[mf][nf], 0, 0, 0);
        acc[mf][nf] = __builtin_amdgcn_mfma_f32_16x16x32_bf16(ah[mf], bl[nf], acc[mf][nf], 0, 0, 0);
        acc[mf][nf] = __builtin_amdgcn_mfma_f32_16x16x32_bf16(al[mf], bh[nf], acc[mf][nf], 0, 0, 0);
      }
    __builtin_amdgcn_s_setprio(0);
  }
#pragma unroll
  for (int mf = 0; mf < 4; mf++)
#pragma unroll
    for (int nf = 0; nf < 4; nf++)
#pragma unroll
      for (int j = 0; j < 4; j++) {
        int m = m0 + wm * 64 + mf * 16 + rg * 4 + j;
        int n = n0 + wn * 64 + nf * 16 + c16;
        qkv[(size_t)m * QKVN + n] = acc[mf][nf][j];
      }
}

// ================= PREP PHASE 2 (fused): rope_q | rope_kf | vt2 | bm =================
__global__ __launch_bounds__(256) void k_prep2(
    const float* __restrict__ qkv, const float* __restrict__ cosb, const float* __restrict__ sinb,
    u16* __restrict__ qf, u16* __restrict__ kf2, u16* __restrict__ vt2, float* __restrict__ bm) {
  __shared__ float vb[64][129];
  const int b = blockIdx.x, tid = threadIdx.x;

  if (b < 4096) {                       // ---- rope q (8 floats / thread) ----
    int p = b * 256 + tid;              // [0, SQ*2048/8)
    int t = p >> 8;
    int col8 = (p & 255) * 8;
    int h = col8 >> 7, d0 = col8 & 127;
    int i0 = d0 >> 1;
    const float* src = qkv + (size_t)t * QKVN + h * 128 + d0;
    float4 a = *(const float4*)src;
    float4 bq = *(const float4*)(src + 4);
    float4 cs = *(const float4*)(cosb + t * 64 + i0);
    float4 sn = *(const float4*)(sinb + t * 64 + i0);
    const float QSC = (float)(1.4426950408889634 * 0.08838834764831843);  // log2e/sqrt(128)
    float xe[4] = {a.x, a.z, bq.x, bq.z}, xo[4] = {a.y, a.w, bq.y, bq.w};
    float cc[4] = {cs.x, cs.y, cs.z, cs.w}, ss[4] = {sn.x, sn.y, sn.z, sn.w};
    u32 pk[4];
#pragma unroll
    for (int jj = 0; jj < 4; jj++) {
      float re = (xe[jj] * cc[jj] - xo[jj] * ss[jj]) * QSC;
      float ro = (xe[jj] * ss[jj] + xo[jj] * cc[jj]) * QSC;
      pk[jj] = (u32)f2h(re) | ((u32)f2h(ro) << 16);
    }
    *(uint4*)(qf + ((size_t)h * SQ + t) * 128 + d0) = make_uint4(pk[0], pk[1], pk[2], pk[3]);
    return;
  }
  if (b < 4608) {                       // ---- rope k -> fragment-major ----
    int r = b - 4096;
    int hk = r & 7, tile = r >> 3;
    u16* dst = kf2 + (size_t)(hk * 64 + tile) * 8192;
#pragma unroll
    for (int rep = 0; rep < 4; rep++) {
      int p = rep * 256 + tid;
      int f = p >> 6, lane = p & 63;
      int dk = f & 3, hf = (f >> 2) & 1, kk = f >> 3;
      int rg = lane >> 4, c16v = lane & 15;
      int t5 = ((c16v >> 2) << 3) | (hf << 2) | (c16v & 3);
      int t = tile * 64 + kk * 32 + t5;
      int d0 = dk * 32 + rg * 8;
      const float* src = qkv + (size_t)t * QKVN + 2048 + hk * 128 + d0;
      float4 a = *(const float4*)src;
      float4 bq = *(const float4*)(src + 4);
      int i0 = d0 >> 1;
      float4 cs = *(const float4*)(cosb + t * 64 + i0);
      float4 sn = *(const float4*)(sinb + t * 64 + i0);
      float xe[4] = {a.x, a.z, bq.x, bq.z}, xo[4] = {a.y, a.w, bq.y, bq.w};
      float cc[4] = {cs.x, cs.y, cs.z, cs.w}, ss[4] = {sn.x, sn.y, sn.z, sn.w};
      u32 pk[4];
#pragma unroll
      for (int jj = 0; jj < 4; jj++) {
        float re = xe[jj] * cc[jj] - xo[jj] * ss[jj];
        float ro = xe[jj] * ss[jj] + xo[jj] * cc[jj];
        pk[jj] = (u32)f2h(re) | ((u32)f2h(ro) << 16);
      }
      *(uint4*)(dst + (size_t)p * 8) = make_uint4(pk[0], pk[1], pk[2], pk[3]);
    }
    return;
  }
  if (b < 5120) {                       // ---- v -> fragment-major via padded-LDS transpose ----
    int r = b - 4608;
    int hk = r & 7, tile = r >> 3;
    int r4 = tid >> 6, cl = (tid & 63) * 2;
#pragma unroll
    for (int it = 0; it < 16; it++) {
      int row = it * 4 + r4;
      float2 v = *(const float2*)(qkv + (size_t)(tile * 64 + row) * QKVN + 3072 + hk * 128 + cl);
      vb[row][cl] = v.x;
      vb[row][cl + 1] = v.y;
    }
    __syncthreads();
    u16* dst = vt2 + (size_t)(hk * 64 + tile) * 8192;
#pragma unroll
    for (int rep = 0; rep < 4; rep++) {
      int p = rep * 256 + tid;
      int g = p >> 6, lane = p & 63;
      int nf = g & 7, kk = g >> 3;
      int rg = lane >> 4, c16v = lane & 15;
      int d = nf * 16 + c16v;
      int tokb = kk * 32 + rg * 8;
      u32 pk[4];
#pragma unroll
      for (int jj = 0; jj < 4; jj++) {
        float v0 = vb[tokb + 2 * jj][d];
        float v1 = vb[tokb + 2 * jj + 1][d];
        pk[jj] = (u32)f2h(v0) | ((u32)f2h(v1) << 16);
      }
      *(uint4*)(dst + (size_t)p * 8) = make_uint4(pk[0], pk[1], pk[2], pk[3]);
    }
    return;
  }
  {                                     // ---- block means (4 units per block, 1 per wave) ----
    int u = (b - 5120) * 4 + (tid >> 6);
    int hk = u >> 5, n = u & 31;
    int i = tid & 63;
    double se = 0.0, so = 0.0;
    for (int t = 0; t < 128; t++) {
      int tt = n * 128 + t;
      float2 eo = *(const float2*)(qkv + (size_t)tt * QKVN + 2048 + hk * 128 + 2 * i);
      float c = cosb[tt * 64 + i], s = sinb[tt * 64 + i];
      se += (double)(eo.x * c - eo.y * s);
      so += (double)(eo.x * s + eo.y * c);
    }
    float* o = bm + ((size_t)(hk * 32 + n)) * 128 + 2 * i;
    o[0] = (float)(se * (1.0 / 128.0));
    o[1] = (float)(so * (1.0 / 128.0));
  }
}

// ---------------- gating: own-block in top-8? (only matters for b>=8) ----------------
__global__ __launch_bounds__(64) void k_gate(const float* __restrict__ qkv,
                                             const float* __restrict__ cosb,
                                             const float* __restrict__ sinb,
                                             const float* __restrict__ bm,
                                             unsigned char* __restrict__ sel) {
  __shared__ float q[64][129];
  __shared__ float bml[32 * 128];
  int bz = blockIdx.x;  // h*48 + (b-8)*2 + half
  int h = bz / 48;
  int rem = bz % 48;
  int b = 8 + (rem >> 1);
  int half = rem & 1;
  int tid = threadIdx.x;
  int hk = h >> 1;
  for (int rr = 0; rr < 64; rr++) {
    int ss = b * 128 + half * 64 + rr;
    float2 eo = *(const float2*)(qkv + (size_t)ss * QKVN + h * 128 + 2 * tid);
    float c = cosb[ss * 64 + tid], sn = sinb[ss * 64 + tid];
    q[rr][2 * tid]     = eo.x * c - eo.y * sn;
    q[rr][2 * tid + 1] = eo.x * sn + eo.y * c;
  }
  for (int o = tid; o < (b + 1) * 128; o += 64) bml[o] = bm[(size_t)hk * 32 * 128 + o];
  __syncthreads();
  int s = b * 128 + half * 64 + tid;
  double gb = 0.0;
  for (int d = 0; d < 128; d++) gb += (double)q[tid][d] * (double)bml[b * 128 + d];
  int cnt = 0;
  for (int n = 0; n < b; n++) {
    double g = 0.0;
    for (int d = 0; d < 128; d++) g += (double)q[tid][d] * (double)bml[n * 128 + d];
    cnt += (g >= gb) ? 1 : 0;
  }
  sel[h * SQ + s] = (cnt <= 7) ? 1 : 0;
}

// ---------------- split-KV flash attention: KVBLK=32, fragment-major LDS dbuf (R5 measured) ----------------
__global__ __launch_bounds__(256) void k_attn_chunk(
    const u16* __restrict__ qf, const u16* __restrict__ kf2, const u16* __restrict__ vt2,
    const unsigned char* __restrict__ sel, u16* __restrict__ po, float* __restrict__ ml) {
  __shared__ u16 lds[2][8192];     // 2 bufs x (K 8KB | V 8KB) = 32KB
  const int L = blockIdx.x;        // [0,1280): laid out so XCD == hk
  const int hk = L & 7;
  const int c = L >> 3;            // [0,160)
  const int h = hk * 2 + (c & 1);
  const int cc = c >> 1;           // [0,80)
  int qb, chunk;
  if (cc < 8)       { qb = cc;                   chunk = 0; }
  else if (cc < 24) { qb = 8 + ((cc - 8) >> 1);  chunk = (cc - 8) & 1; }
  else if (cc < 48) { qb = 16 + (cc - 24) / 3;   chunk = (cc - 24) % 3; }
  else              { qb = 24 + ((cc - 48) >> 2); chunk = (cc - 48) & 3; }
  const int nt128 = (qb < 8) ? 8 : (qb + 1);
  const int t0 = chunk * 32;                       // 32-token units
  const int t1 = (t0 + 32 < nt128 * 4) ? t0 + 32 : nt128 * 4;
  const int tid = threadIdx.x;
  const int lane = tid & 63, wid = tid >> 6;
  const int rg = lane >> 4, c16 = lane & 15;
  const bool hasMask = (qb >= 8);

  half8 aq[2][4];
#pragma unroll
  for (int mi = 0; mi < 2; mi++)
#pragma unroll
    for (int dk = 0; dk < 4; dk++) {
      int srow = qb * 128 + wid * 32 + mi * 16 + c16;
      aq[mi][dk] = *(const half8*)(qf + ((size_t)h * SQ + srow) * 128 + dk * 32 + rg * 8);
    }

  bool os2[2] = {true, true};
  if (hasMask) {
#pragma unroll
    for (int mi = 0; mi < 2; mi++)
      os2[mi] = sel[h * SQ + qb * 128 + wid * 32 + mi * 16 + c16] != 0;
  }

  f32x4 accO[2][8];
#pragma unroll
  for (int mi = 0; mi < 2; mi++)
#pragma unroll
    for (int nf = 0; nf < 8; nf++) accO[mi][nf] = (f32x4){0.f, 0.f, 0.f, 0.f};
  float mrun[2] = {-1e30f, -1e30f}, lrun[2] = {0.f, 0.f};

  const u16* kbase = kf2 + (size_t)hk * 64 * 8192;   // 32-tile n at offset n*4096
  const u16* vbase = vt2 + (size_t)hk * 64 * 8192;

  auto stage = [&](int b, int n) {
    const u16* ks = kbase + (size_t)n * 4096;
    const u16* vs = vbase + (size_t)n * 4096;
#pragma unroll
    for (int r = 0; r < 2; r++) {
      gll16(ks + r * 2048 + wid * 512 + lane * 8, &lds[b][r * 2048 + wid * 512]);
      gll16(vs + r * 2048 + wid * 512 + lane * 8, &lds[b][4096 + r * 2048 + wid * 512]);
    }
  };

  stage(0, t0);

  for (int n = t0; n < t1; n++) {
    const int cur = (n - t0) & 1;
    __syncthreads();
    if (n + 1 < t1) stage(cur ^ 1, n + 1);
    const u16* lb = &lds[cur][0];

    f32x4 st[2][2];                  // [hf][mi]
#pragma unroll
    for (int hf = 0; hf < 2; hf++)
#pragma unroll
      for (int mi = 0; mi < 2; mi++) st[hf][mi] = (f32x4){0.f, 0.f, 0.f, 0.f};

    __builtin_amdgcn_s_setprio(1);
#pragma unroll
    for (int hf = 0; hf < 2; hf++) {
      half8 ka[4];
#pragma unroll
      for (int dk = 0; dk < 4; dk++)
        ka[dk] = *(const half8*)(lb + (hf * 4 + dk) * 512 + lane * 8);
#pragma unroll
      for (int dk = 0; dk < 4; dk++) {
        st[hf][0] = __builtin_amdgcn_mfma_f32_16x16x32_f16(ka[dk], aq[0][dk], st[hf][0], 0, 0, 0);
        st[hf][1] = __builtin_amdgcn_mfma_f32_16x16x32_f16(ka[dk], aq[1][dk], st[hf][1], 0, 0, 0);
      }
    }
    __builtin_amdgcn_s_setprio(0);

    if (hasMask && n >= 4 * qb) {
#pragma unroll
      for (int mi = 0; mi < 2; mi++) {
        if (!os2[mi]) {
          int row = qb * 128 + wid * 32 + mi * 16 + c16;
#pragma unroll
          for (int hf = 0; hf < 2; hf++)
#pragma unroll
            for (int j = 0; j < 4; j++) {
              int tg = n * 32 + rg * 8 + hf * 4 + j;
              if (tg > row) st[hf][mi][j] = -1e30f;
            }
        }
      }
    }

#pragma unroll
    for (int mi = 0; mi < 2; mi++) {
      float mt = st[0][mi][0];
#pragma unroll
      for (int hf = 0; hf < 2; hf++)
#pragma unroll
        for (int j = 0; j < 4; j++)
          if (hf | j) mt = fmaxf(mt, st[hf][mi][j]);
      mt = fmaxf(mt, __shfl_xor(mt, 16, 64));
      mt = fmaxf(mt, __shfl_xor(mt, 32, 64));
      if (!__all(mt <= mrun[mi] + 8.f)) {
        float mnew = fmaxf(mrun[mi], mt);
        float sc = exp2f(mrun[mi] - mnew);
        mrun[mi] = mnew;
        lrun[mi] *= sc;
#pragma unroll
        for (int nf = 0; nf < 8; nf++) accO[mi][nf] *= sc;
      }
      float ps = 0.f;
#pragma unroll
      for (int hf = 0; hf < 2; hf++)
#pragma unroll
        for (int j = 0; j < 4; j++) {
          float p = exp2f(st[hf][mi][j] - mrun[mi]);
          st[hf][mi][j] = p;
          ps += p;
        }
      ps += __shfl_xor(ps, 16, 64);
      ps += __shfl_xor(ps, 32, 64);
      lrun[mi] += ps;
    }

    half8 pa[2];
#pragma unroll
    for (int mi = 0; mi < 2; mi++) {
      union { half8 v; _Float16 e[8]; } pu;
#pragma unroll
      for (int hf = 0; hf < 2; hf++)
#pragma unroll
        for (int j = 0; j < 4; j++)
          pu.e[hf * 4 + j] = (_Float16)st[hf][mi][j];
      pa[mi] = pu.v;
    }

    __builtin_amdgcn_s_setprio(1);
#pragma unroll
    for (int nf = 0; nf < 8; nf++) {
      half8 va = *(const half8*)(lb + 4096 + nf * 512 + lane * 8);
      accO[0][nf] = __builtin_amdgcn_mfma_f32_16x16x32_f16(va, pa[0], accO[0][nf], 0, 0, 0);
      accO[1][nf] = __builtin_amdgcn_mfma_f32_16x16x32_f16(va, pa[1], accO[1][nf], 0, 0, 0);
    }
    __builtin_amdgcn_s_setprio(0);
  }

  const int pidx = h * 80 + cidx(qb) + chunk;
  u16* pob = po + (size_t)pidx * 16384;
#pragma unroll
  for (int mi = 0; mi < 2; mi++) {
    float inv = 1.0f / lrun[mi];
    int row = wid * 32 + mi * 16 + c16;
#pragma unroll
    for (int nf = 0; nf < 8; nf++) {
      u32 p0 = (u32)f2h(accO[mi][nf][0] * inv) | ((u32)f2h(accO[mi][nf][1] * inv) << 16);
      u32 p1 = (u32)f2h(accO[mi][nf][2] * inv) | ((u32)f2h(accO[mi][nf][3] * inv) << 16);
      *(uint2*)&pob[row * 128 + nf * 16 + rg * 4] = make_uint2(p0, p1);
    }
    if (rg == 0)
      ml[(size_t)pidx * 128 + row] = mrun[mi] + log2f(lrun[mi]);
  }
}

// ---------------- combine split-KV partials -> attn (f16) ----------------
__global__ __launch_bounds__(256) void k_attn_combine(
    const u16* __restrict__ po, const float* __restrict__ ml, u16* __restrict__ attn) {
  const int qb = blockIdx.x, h = blockIdx.y;
  const int nc = (qb < 8) ? 1 : (qb < 16) ? 2 : (qb < 24) ? 3 : 4;
  const int base = h * 80 + cidx(qb);
  const int tid = threadIdx.x;
  const int r = tid >> 1, h64 = (tid & 1) * 64;
  float mp[4], M = -1e30f;
#pragma unroll
  for (int ci = 0; ci < 4; ci++) {
    mp[ci] = (ci < nc) ? ml[(size_t)(base + ci) * 128 + r] : -1e30f;
    M = fmaxf(M, mp[ci]);
  }
  float w[4], Ws = 0.f;
#pragma unroll
  for (int ci = 0; ci < 4; ci++) { w[ci] = exp2f(mp[ci] - M); Ws += (ci < nc) ? w[ci] : 0.f; }
  float inv = 1.0f / Ws;
  for (int d = 0; d < 64; d += 4) {
    float a[4] = {0.f, 0.f, 0.f, 0.f};
#pragma unroll
    for (int ci = 0; ci < 4; ci++) {
      if (ci < nc) {
        uint2 u = *(const uint2*)&po[(size_t)(base + ci) * 16384 + r * 128 + h64 + d];
        a[0] += w[ci] * h2f((u16)(u.x & 0xffff));
        a[1] += w[ci] * h2f((u16)(u.x >> 16));
        a[2] += w[ci] * h2f((u16)(u.y & 0xffff));
        a[3] += w[ci] * h2f((u16)(u.y >> 16));
      }
    }
    u32 p0 = (u32)f2h(a[0] * inv) | ((u32)f2h(a[1] * inv) << 16);
    u32 p1 = (u32)f2h(a[2] * inv) | ((u32)f2h(a[3] * inv) << 16);
    *(uint2*)&attn[(size_t)(qb * 128 + r) * DIMM + h * 128 + h64 + d] = make_uint2(p0, p1);
  }
}

// ---------------- out = attn @ wo (f16 GEMM, fp32 out, BK=64 DBUF stage-early, XCD-swizzled) ----------------
__global__ __launch_bounds__(256) void k_gemm_out(
    const u16* __restrict__ attn, const u16* __restrict__ wot, float* __restrict__ out) {
  __shared__ u16 lds[2][16384];  // per buf: A(128x64) | B(128x64) u16, 32KB; dbuf 64KB
  const int tid = threadIdx.x;
  const int lane = tid & 63, wid = tid >> 6;
  const int rg = lane >> 4, c16 = lane & 15;
  const int bid0 = blockIdx.y * 16 + blockIdx.x;           // 512 blocks
  const int swz = (bid0 & 7) * 64 + (bid0 >> 3);
  const int m0 = (swz >> 4) * 128, n0 = (swz & 15) * 128;
  const int wm = wid >> 1, wn = wid & 1;
  const u16* gsrc = (wid < 2) ? attn + (size_t)m0 * 2048 : wot + (size_t)n0 * 2048;
  const int sr = lane >> 3, scn = lane & 7;

  f32x4 acc[4][4];
#pragma unroll
  for (int a = 0; a < 4; a++)
#pragma unroll
    for (int b = 0; b < 4; b++) acc[a][b] = (f32x4){0.f, 0.f, 0.f, 0.f};

  auto stage = [&](int bi, int k0) {
#pragma unroll
    for (int i = 0; i < 8; i++) {
      int slot = wid * 8 + i;          // [0,32): 0..15 A, 16..31 B
      int s2 = slot & 15;
      int r = s2 * 8 + sr;
      int cs = (scn ^ (r & 7)) * 8;
      gll16(gsrc + (size_t)r * 2048 + k0 + cs, &lds[bi][slot * 512]);
    }
  };

  stage(0, 0);

  for (int ks = 0; ks < 32; ks++) {
    __syncthreads();                 // buf[ks&1] staged; prev buf's reads done
    if (ks + 1 < 32) stage((ks & 1) ^ 1, (ks + 1) * 64);  // overlap with this step's compute
    const u16* lb = lds[ks & 1];
#pragma unroll
    for (int kk = 0; kk < 2; kk++) {
      half8 a[4], b[4];
      int ch = kk * 4 + rg;
#pragma unroll
      for (int mf = 0; mf < 4; mf++) {
        int m = wm * 64 + mf * 16 + c16;
        a[mf] = *(const half8*)(lb + m * 64 + ((ch ^ (m & 7)) * 8));
      }
#pragma unroll
      for (int nf = 0; nf < 4; nf++) {
        int n = wn * 64 + nf * 16 + c16;
        b[nf] = *(const half8*)(lb + 8192 + n * 64 + ((ch ^ (n & 7)) * 8));
      }
      __builtin_amdgcn_s_setprio(1);
#pragma unroll
      for (int mf = 0; mf < 4; mf++)
#pragma unroll
        for (int nf = 0; nf < 4; nf++)
          acc[mf][nf] = __builtin_amdgcn_mfma_f32_16x16x32_f16(a[mf], b[nf], acc[mf][nf], 0, 0, 0);
      __builtin_amdgcn_s_setprio(0);
    }
  }
#pragma unroll
  for (int mf = 0; mf < 4; mf++)
#pragma unroll
    for (int nf = 0; nf < 4; nf++)
#pragma unroll
      for (int j = 0; j < 4; j++) {
        int m = m0 + wm * 64 + mf * 16 + rg * 4 + j;
        int n = n0 + wn * 64 + nf * 16 + c16;
        out[(size_t)m * DIMM + n] = acc[mf][nf][j];
      }
}

extern "C" void kernel_launch(void* const* d_in, const int* in_sizes, int n_in,
                              void* d_out, int out_size, void* d_ws, size_t ws_size,
                              hipStream_t stream) {
  (void)in_sizes; (void)n_in; (void)out_size; (void)ws_size;
  const float* x  = (const float*)d_in[0];
  const float* wq = (const float*)d_in[1];
  const float* wk = (const float*)d_in[2];
  const float* wv = (const float*)d_in[3];
  const float* wo = (const float*)d_in[4];
  float* out = (float*)d_out;

  char* ws = (char*)d_ws;
  const size_t MB = 1024 * 1024;
  // Region A (128MB): xh|xl|wth|wtl|qkv during projection; aliased by po|ml for split-KV
  char* A = ws;
  u16*   xh  = (u16*)(A);
  u16*   xl  = (u16*)(A + 16 * MB);
  u16*   wth = (u16*)(A + 32 * MB);
  u16*   wtl = (u16*)(A + 48 * MB);
  float* qkv = (float*)(A + 64 * MB);
  u16*   po  = (u16*)(A);              // 40MB (1280 x 128 x 128 f16), overlays dead buffers
  float* ml  = (float*)(A + 48 * MB);  // 0.64MB, overlays dead wtl
  // Region B (persistent)
  char* B = ws + 128 * MB;
  size_t off = 0;
  auto alloc = [&](size_t b) { char* p = B + off; off += (b + 255) & ~(size_t)255; return p; };
  u16*   wot  = (u16*)alloc((size_t)DIMM * DIMM * 2);
  float* cosb = (float*)alloc((size_t)SQ * 64 * 4);
  float* sinb = (float*)alloc((size_t)SQ * 64 * 4);
  u16*   qf   = (u16*)alloc((size_t)16 * SQ * 128 * 2);
  u16*   kf2  = (u16*)alloc((size_t)8 * SQ * 128 * 2);
  u16*   vt2  = (u16*)alloc((size_t)8 * 128 * SQ * 2);
  float* bm   = (float*)alloc((size_t)8 * 32 * 128 * 4);
  unsigned char* sel = (unsigned char*)alloc((size_t)16 * SQ);
  u16*   attn = (u16*)alloc((size_t)SQ * DIMM * 2);

  k_prep1<<<12288, 256, 0, stream>>>(x, wq, wk, wv, wo, cosb, sinb, xh, xl, wth, wtl, wot);
  k_gemm_qkv<<<dim3(32, 32), 256, 0, stream>>>(xh, xl, wth, wtl, qkv);
  k_prep2<<<5184, 256, 0, stream>>>(qkv, cosb, sinb, qf, kf2, vt2, bm);
  k_gate<<<16 * 48, 64, 0, stream>>>(qkv, cosb, sinb, bm, sel);
  // qkv (and xh/xl/wth/wtl) are dead past this point -> po/ml alias them
  k_attn_chunk<<<1280, 256, 0, stream>>>(qf, kf2, vt2, sel, po, ml);
  k_attn_combine<<<dim3(32, 16), 256, 0, stream>>>(po, ml, attn);
  k_gemm_out<<<dim3(16, 32), 256, 0, stream>>>(attn, wot, out);
}

// Round 12
// 544.924 us; speedup vs baseline: 1.0747x; 1.0241x over previous
//
#include <hip/hip_runtime.h>
#include <hip/hip_fp16.h>

#define SQ   4096
#define DIMM 2048
#define QKVN 4096   // 2048 q | 1024 k | 1024 v

typedef unsigned short u16;
typedef unsigned int u32;
typedef __attribute__((ext_vector_type(8))) short    short8;  // bf16x8 frag
typedef __attribute__((ext_vector_type(8))) _Float16 half8;   // f16x8 frag
typedef __attribute__((ext_vector_type(4))) float    f32x4;

__device__ __forceinline__ u16 f2bf(float f) {
  u32 u = __float_as_uint(f);
  u32 r = u + 0x7fffu + ((u >> 16) & 1u);
  return (u16)(r >> 16);
}
__device__ __forceinline__ float bf2f(u16 h) { return __uint_as_float(((u32)h) << 16); }
__device__ __forceinline__ u16 f2h(float f) { return __half_as_ushort(__float2half(f)); }
__device__ __forceinline__ float h2f(u16 h) { union { u16 u; _Float16 f; } c; c.u = h; return (float)c.f; }

__device__ __forceinline__ void gll16(const void* g, void* l) {
  __builtin_amdgcn_global_load_lds((const __attribute__((address_space(1))) void*)g,
                                   (__attribute__((address_space(3))) void*)l, 16, 0, 0);
}

// chunk-slot cumulative index per head (pidx layout; partition-agnostic)
__device__ __host__ __forceinline__ int cidx(int qb) {
  return qb < 8 ? qb : qb < 16 ? 8 + (qb - 8) * 2 : qb < 24 ? 24 + (qb - 16) * 3 : 48 + (qb - 24) * 4;
}

// ================= PREP PHASE 1 (fused): tables | split_x | W transposes =================
__global__ __launch_bounds__(256) void k_prep1(
    const float* __restrict__ x, const float* __restrict__ wq, const float* __restrict__ wk,
    const float* __restrict__ wv, const float* __restrict__ wo,
    float* __restrict__ cosb, float* __restrict__ sinb,
    u16* __restrict__ xh, u16* __restrict__ xl,
    u16* __restrict__ wth, u16* __restrict__ wtl, u16* __restrict__ wot) {
  __shared__ float t[64][65];
  const int b = blockIdx.x, tid = threadIdx.x;

  if (b < 1024) {                       // ---- RoPE tables ----
    int idx = b * 256 + tid;            // SQ*64
    int pos = idx >> 6, i = idx & 63;
    double f = 1.0 / pow(10000.0, (double)i / 64.0);
    float inv = (float)f;
    float ang = (float)pos * inv;
    cosb[idx] = (float)cos((double)ang);
    sinb[idx] = (float)sin((double)ang);
    return;
  }
  if (b < 9216) {                       // ---- split x into bf16 hi/lo ----
    size_t base = ((size_t)(b - 1024) * 256 + tid) * 4;
    float4 v = *(const float4*)(x + base);
    float vv[4] = {v.x, v.y, v.z, v.w};
    u16 hh[4], ll[4];
#pragma unroll
    for (int j = 0; j < 4; j++) {
      hh[j] = f2bf(vv[j]);
      ll[j] = f2bf(vv[j] - bf2f(hh[j]));
    }
    *(uint2*)(xh + base) = make_uint2((u32)hh[0] | ((u32)hh[1] << 16), (u32)hh[2] | ((u32)hh[3] << 16));
    *(uint2*)(xl + base) = make_uint2((u32)ll[0] | ((u32)ll[1] << 16), (u32)ll[2] | ((u32)ll[3] << 16));
    return;
  }
  // ---- weight transposes (shared-tile) ----
  const float* src; int N, rowOff, bx, by; bool f16only = false;
  if (b < 10240)      { int r = b - 9216;  src = wq; N = 2048; rowOff = 0;    bx = r & 31, by = r >> 5; }
  else if (b < 10752) { int r = b - 10240; src = wk; N = 1024; rowOff = 2048; bx = r & 15, by = r >> 4; }
  else if (b < 11264) { int r = b - 10752; src = wv; N = 1024; rowOff = 3072; bx = r & 15, by = r >> 4; }
  else                { int r = b - 11264; src = wo; N = 2048; rowOff = 0;    bx = r & 31, by = r >> 5; f16only = true; }
  int n0 = bx * 64, k0 = by * 64;
  int c = tid & 63, r4 = tid >> 6;
#pragma unroll
  for (int it = 0; it < 16; it++) {
    int kk = it * 4 + r4;
    t[kk][c] = src[(size_t)(k0 + kk) * N + n0 + c];
  }
  __syncthreads();
#pragma unroll
  for (int it = 0; it < 16; it++) {
    int nn = it * 4 + r4;
    float v = t[c][nn];
    size_t o = (size_t)(rowOff + n0 + nn) * 2048 + k0 + c;
    if (f16only) {
      wot[o] = f2h(v);
    } else {
      u16 hh = f2bf(v);
      wth[o] = hh;
      wtl[o] = f2bf(v - bf2f(hh));
    }
  }
}

// ---------------- QKV projection: bf16x3 split GEMM, 128x128 tile, BK=32 dbuf.
// XCD mapping: 4 m-tiles pinned per XCD (A panels L2-resident), n-major order. (R8 measured: 180us) ----
__global__ __launch_bounds__(256) void k_gemm_qkv(
    const u16* __restrict__ xh, const u16* __restrict__ xl,
    const u16* __restrict__ wth, const u16* __restrict__ wtl,
    float* __restrict__ qkv) {
  __shared__ u16 lds[2][16384];   // per buf: Ah|Al|Bh|Bl, each 128x32 u16 (4096), 32KB/buf
  const int tid = threadIdx.x;
  const int lane = tid & 63, wid = tid >> 6;
  const int rg = lane >> 4, c16 = lane & 15;
  const int bid0 = blockIdx.y * 32 + blockIdx.x;           // 1024 blocks
  const int xcd = bid0 & 7, local = bid0 >> 3;             // local in [0,128)
  const int m0 = (xcd * 4 + (local & 3)) * 128;            // m-tiles pinned per XCD
  const int n0 = (local >> 2) * 128;                       // n-major within XCD
  const int wm = wid >> 1, wn = wid & 1;
  const u16* gsrc = (wid == 0) ? xh + (size_t)m0 * 2048
                  : (wid == 1) ? xl + (size_t)m0 * 2048
                  : (wid == 2) ? wth + (size_t)n0 * 2048
                               : wtl + (size_t)n0 * 2048;
  const int srow4 = lane >> 2;   // 0..15
  const int pc = lane & 3;       // physical 16B chunk within 64B row

  f32x4 acc[4][4];
#pragma unroll
  for (int a = 0; a < 4; a++)
#pragma unroll
    for (int b = 0; b < 4; b++) acc[a][b] = (f32x4){0.f, 0.f, 0.f, 0.f};

  auto stage = [&](int b, int k0) {
#pragma unroll
    for (int i = 0; i < 8; i++) {
      int r = i * 16 + srow4;
      int cl = pc ^ ((r >> 1) & 3);
      gll16(gsrc + (size_t)r * 2048 + k0 + cl * 8, &lds[b][wid * 4096 + i * 512 + lane * 8]);
    }
  };

  stage(0, 0);

  for (int ks = 0; ks < 64; ks++) {
    __syncthreads();
    if (ks + 1 < 64) stage((ks & 1) ^ 1, (ks + 1) * 32);
    const u16* lb = lds[ks & 1];

    short8 ah[4], al[4], bh[4], bl[4];
#pragma unroll
    for (int mf = 0; mf < 4; mf++) {
      int m = wm * 64 + mf * 16 + c16;
      int xo = m * 32 + ((rg ^ ((m >> 1) & 3)) * 8);
      ah[mf] = *(const short8*)(lb + xo);
      al[mf] = *(const short8*)(lb + 4096 + xo);
    }
#pragma unroll
    for (int nf = 0; nf < 4; nf++) {
      int n = wn * 64 + nf * 16 + c16;
      int xo = n * 32 + ((rg ^ ((n >> 1) & 3)) * 8);
      bh[nf] = *(const short8*)(lb + 8192 + xo);
      bl[nf] = *(const short8*)(lb + 12288 + xo);
    }
    __builtin_amdgcn_s_setprio(1);
#pragma unroll
    for (int mf = 0; mf < 4; mf++)
#pragma unroll
      for (int nf = 0; nf < 4; nf++) {
        acc[mf][nf] = __builtin_amdgcn_mfma_f32_16x16x32_bf16(ah[mf], bh[nf], acc[mf][nf], 0, 0, 0);
        acc[mf][nf] = __builtin_amdgcn_mfma_f32_16x16x32_bf16(ah[mf], bl[nf], acc[mf][nf], 0, 0, 0);
        acc[mf][nf] = __builtin_amdgcn_mfma_f32_16x16x32_bf16(al[mf], bh[nf], acc[mf][nf], 0, 0, 0);
      }
    __builtin_amdgcn_s_setprio(0);
  }
#pragma unroll
  for (int mf = 0; mf < 4; mf++)
#pragma unroll
    for (int nf = 0; nf < 4; nf++)
#pragma unroll
      for (int j = 0; j < 4; j++) {
        int m = m0 + wm * 64 + mf * 16 + rg * 4 + j;
        int n = n0 + wn * 64 + nf * 16 + c16;
        qkv[(size_t)m * QKVN + n] = acc[mf][nf][j];
      }
}

// ================= PREP PHASE 2 (fused): rope_q | rope_kf | vt2 | bm =================
__global__ __launch_bounds__(256) void k_prep2(
    const float* __restrict__ qkv, const float* __restrict__ cosb, const float* __restrict__ sinb,
    u16* __restrict__ qf, u16* __restrict__ kf2, u16* __restrict__ vt2, float* __restrict__ bm) {
  __shared__ float vb[64][129];
  const int b = blockIdx.x, tid = threadIdx.x;

  if (b < 4096) {                       // ---- rope q (8 floats / thread) ----
    int p = b * 256 + tid;              // [0, SQ*2048/8)
    int t = p >> 8;
    int col8 = (p & 255) * 8;
    int h = col8 >> 7, d0 = col8 & 127;
    int i0 = d0 >> 1;
    const float* src = qkv + (size_t)t * QKVN + h * 128 + d0;
    float4 a = *(const float4*)src;
    float4 bq = *(const float4*)(src + 4);
    float4 cs = *(const float4*)(cosb + t * 64 + i0);
    float4 sn = *(const float4*)(sinb + t * 64 + i0);
    const float QSC = (float)(1.4426950408889634 * 0.08838834764831843);  // log2e/sqrt(128)
    float xe[4] = {a.x, a.z, bq.x, bq.z}, xo[4] = {a.y, a.w, bq.y, bq.w};
    float cc[4] = {cs.x, cs.y, cs.z, cs.w}, ss[4] = {sn.x, sn.y, sn.z, sn.w};
    u32 pk[4];
#pragma unroll
    for (int jj = 0; jj < 4; jj++) {
      float re = (xe[jj] * cc[jj] - xo[jj] * ss[jj]) * QSC;
      float ro = (xe[jj] * ss[jj] + xo[jj] * cc[jj]) * QSC;
      pk[jj] = (u32)f2h(re) | ((u32)f2h(ro) << 16);
    }
    *(uint4*)(qf + ((size_t)h * SQ + t) * 128 + d0) = make_uint4(pk[0], pk[1], pk[2], pk[3]);
    return;
  }
  if (b < 4608) {                       // ---- rope k -> fragment-major ----
    int r = b - 4096;
    int hk = r & 7, tile = r >> 3;
    u16* dst = kf2 + (size_t)(hk * 64 + tile) * 8192;
#pragma unroll
    for (int rep = 0; rep < 4; rep++) {
      int p = rep * 256 + tid;
      int f = p >> 6, lane = p & 63;
      int dk = f & 3, hf = (f >> 2) & 1, kk = f >> 3;
      int rg = lane >> 4, c16v = lane & 15;
      int t5 = ((c16v >> 2) << 3) | (hf << 2) | (c16v & 3);
      int t = tile * 64 + kk * 32 + t5;
      int d0 = dk * 32 + rg * 8;
      const float* src = qkv + (size_t)t * QKVN + 2048 + hk * 128 + d0;
      float4 a = *(const float4*)src;
      float4 bq = *(const float4*)(src + 4);
      int i0 = d0 >> 1;
      float4 cs = *(const float4*)(cosb + t * 64 + i0);
      float4 sn = *(const float4*)(sinb + t * 64 + i0);
      float xe[4] = {a.x, a.z, bq.x, bq.z}, xo[4] = {a.y, a.w, bq.y, bq.w};
      float cc[4] = {cs.x, cs.y, cs.z, cs.w}, ss[4] = {sn.x, sn.y, sn.z, sn.w};
      u32 pk[4];
#pragma unroll
      for (int jj = 0; jj < 4; jj++) {
        float re = xe[jj] * cc[jj] - xo[jj] * ss[jj];
        float ro = xe[jj] * ss[jj] + xo[jj] * cc[jj];
        pk[jj] = (u32)f2h(re) | ((u32)f2h(ro) << 16);
      }
      *(uint4*)(dst + (size_t)p * 8) = make_uint4(pk[0], pk[1], pk[2], pk[3]);
    }
    return;
  }
  if (b < 5120) {                       // ---- v -> fragment-major via padded-LDS transpose ----
    int r = b - 4608;
    int hk = r & 7, tile = r >> 3;
    int r4 = tid >> 6, cl = (tid & 63) * 2;
#pragma unroll
    for (int it = 0; it < 16; it++) {
      int row = it * 4 + r4;
      float2 v = *(const float2*)(qkv + (size_t)(tile * 64 + row) * QKVN + 3072 + hk * 128 + cl);
      vb[row][cl] = v.x;
      vb[row][cl + 1] = v.y;
    }
    __syncthreads();
    u16* dst = vt2 + (size_t)(hk * 64 + tile) * 8192;
#pragma unroll
    for (int rep = 0; rep < 4; rep++) {
      int p = rep * 256 + tid;
      int g = p >> 6, lane = p & 63;
      int nf = g & 7, kk = g >> 3;
      int rg = lane >> 4, c16v = lane & 15;
      int d = nf * 16 + c16v;
      int tokb = kk * 32 + rg * 8;
      u32 pk[4];
#pragma unroll
      for (int jj = 0; jj < 4; jj++) {
        float v0 = vb[tokb + 2 * jj][d];
        float v1 = vb[tokb + 2 * jj + 1][d];
        pk[jj] = (u32)f2h(v0) | ((u32)f2h(v1) << 16);
      }
      *(uint4*)(dst + (size_t)p * 8) = make_uint4(pk[0], pk[1], pk[2], pk[3]);
    }
    return;
  }
  {                                     // ---- block means (4 units per block, 1 per wave) ----
    int u = (b - 5120) * 4 + (tid >> 6);
    int hk = u >> 5, n = u & 31;
    int i = tid & 63;
    double se = 0.0, so = 0.0;
    for (int t = 0; t < 128; t++) {
      int tt = n * 128 + t;
      float2 eo = *(const float2*)(qkv + (size_t)tt * QKVN + 2048 + hk * 128 + 2 * i);
      float c = cosb[tt * 64 + i], s = sinb[tt * 64 + i];
      se += (double)(eo.x * c - eo.y * s);
      so += (double)(eo.x * s + eo.y * c);
    }
    float* o = bm + ((size_t)(hk * 32 + n)) * 128 + 2 * i;
    o[0] = (float)(se * (1.0 / 128.0));
    o[1] = (float)(so * (1.0 / 128.0));
  }
}

// ---------------- gating: own-block in top-8? (only matters for b>=8) ----------------
__global__ __launch_bounds__(64) void k_gate(const float* __restrict__ qkv,
                                             const float* __restrict__ cosb,
                                             const float* __restrict__ sinb,
                                             const float* __restrict__ bm,
                                             unsigned char* __restrict__ sel) {
  __shared__ float q[64][129];
  __shared__ float bml[32 * 128];
  int bz = blockIdx.x;  // h*48 + (b-8)*2 + half
  int h = bz / 48;
  int rem = bz % 48;
  int b = 8 + (rem >> 1);
  int half = rem & 1;
  int tid = threadIdx.x;
  int hk = h >> 1;
  for (int rr = 0; rr < 64; rr++) {
    int ss = b * 128 + half * 64 + rr;
    float2 eo = *(const float2*)(qkv + (size_t)ss * QKVN + h * 128 + 2 * tid);
    float c = cosb[ss * 64 + tid], sn = sinb[ss * 64 + tid];
    q[rr][2 * tid]     = eo.x * c - eo.y * sn;
    q[rr][2 * tid + 1] = eo.x * sn + eo.y * c;
  }
  for (int o = tid; o < (b + 1) * 128; o += 64) bml[o] = bm[(size_t)hk * 32 * 128 + o];
  __syncthreads();
  int s = b * 128 + half * 64 + tid;
  double gb = 0.0;
  for (int d = 0; d < 128; d++) gb += (double)q[tid][d] * (double)bml[b * 128 + d];
  int cnt = 0;
  for (int n = 0; n < b; n++) {
    double g = 0.0;
    for (int d = 0; d < 128; d++) g += (double)q[tid][d] * (double)bml[n * 128 + d];
    cnt += (g >= gb) ? 1 : 0;
  }
  sel[h * SQ + s] = (cnt <= 7) ? 1 : 0;
}

// ---------------- split-KV flash attention: KVBLK=32, fragment-major LDS dbuf.
// R11: equalized chunk partitions (no dwarf blocks) + big-work-first launch order. ----------------
__global__ __launch_bounds__(256) void k_attn_chunk(
    const u16* __restrict__ qf, const u16* __restrict__ kf2, const u16* __restrict__ vt2,
    const unsigned char* __restrict__ sel, u16* __restrict__ po, float* __restrict__ ml) {
  __shared__ u16 lds[2][8192];     // 2 bufs x (K 8KB | V 8KB) = 32KB
  const int L = blockIdx.x;        // [0,1280): laid out so XCD == hk
  const int hk = L & 7;
  const int c = L >> 3;            // [0,160)
  const int h = hk * 2 + (c & 1);
  const int cc = c >> 1;           // [0,80)
  // big-first ordering: qb 0..7 (32u) first, then qb 31..8 descending.
  int qb, chunk, nc;
  if (cc < 8)       { qb = cc;                    chunk = 0;             nc = 1; }
  else if (cc < 40) { qb = 31 - ((cc - 8) >> 2);  chunk = (cc - 8) & 3;  nc = 4; }
  else if (cc < 64) { qb = 23 - (cc - 40) / 3;    chunk = (cc - 40) % 3; nc = 3; }
  else              { qb = 15 - ((cc - 64) >> 1); chunk = (cc - 64) & 1; nc = 2; }
  // equalized token-unit ranges (32-token units)
  const int units = (qb < 8) ? 32 : 4 * (qb + 1);
  const int ubase = units / nc, urem = units % nc;
  const int t0 = chunk * ubase + (chunk < urem ? chunk : urem);
  const int t1 = t0 + ubase + (chunk < urem ? 1 : 0);
  const int tid = threadIdx.x;
  const int lane = tid & 63, wid = tid >> 6;
  const int rg = lane >> 4, c16 = lane & 15;
  const bool hasMask = (qb >= 8);

  half8 aq[2][4];
#pragma unroll
  for (int mi = 0; mi < 2; mi++)
#pragma unroll
    for (int dk = 0; dk < 4; dk++) {
      int srow = qb * 128 + wid * 32 + mi * 16 + c16;
      aq[mi][dk] = *(const half8*)(qf + ((size_t)h * SQ + srow) * 128 + dk * 32 + rg * 8);
    }

  bool os2[2] = {true, true};
  if (hasMask) {
#pragma unroll
    for (int mi = 0; mi < 2; mi++)
      os2[mi] = sel[h * SQ + qb * 128 + wid * 32 + mi * 16 + c16] != 0;
  }

  f32x4 accO[2][8];
#pragma unroll
  for (int mi = 0; mi < 2; mi++)
#pragma unroll
    for (int nf = 0; nf < 8; nf++) accO[mi][nf] = (f32x4){0.f, 0.f, 0.f, 0.f};
  float mrun[2] = {-1e30f, -1e30f}, lrun[2] = {0.f, 0.f};

  const u16* kbase = kf2 + (size_t)hk * 64 * 8192;   // 32-tile n at offset n*4096
  const u16* vbase = vt2 + (size_t)hk * 64 * 8192;

  auto stage = [&](int b, int n) {
    const u16* ks = kbase + (size_t)n * 4096;
    const u16* vs = vbase + (size_t)n * 4096;
#pragma unroll
    for (int r = 0; r < 2; r++) {
      gll16(ks + r * 2048 + wid * 512 + lane * 8, &lds[b][r * 2048 + wid * 512]);
      gll16(vs + r * 2048 + wid * 512 + lane * 8, &lds[b][4096 + r * 2048 + wid * 512]);
    }
  };

  stage(0, t0);

  for (int n = t0; n < t1; n++) {
    const int cur = (n - t0) & 1;
    __syncthreads();
    if (n + 1 < t1) stage(cur ^ 1, n + 1);
    const u16* lb = &lds[cur][0];

    f32x4 st[2][2];                  // [hf][mi]
#pragma unroll
    for (int hf = 0; hf < 2; hf++)
#pragma unroll
      for (int mi = 0; mi < 2; mi++) st[hf][mi] = (f32x4){0.f, 0.f, 0.f, 0.f};

    __builtin_amdgcn_s_setprio(1);
#pragma unroll
    for (int hf = 0; hf < 2; hf++) {
      half8 ka[4];
#pragma unroll
      for (int dk = 0; dk < 4; dk++)
        ka[dk] = *(const half8*)(lb + (hf * 4 + dk) * 512 + lane * 8);
#pragma unroll
      for (int dk = 0; dk < 4; dk++) {
        st[hf][0] = __builtin_amdgcn_mfma_f32_16x16x32_f16(ka[dk], aq[0][dk], st[hf][0], 0, 0, 0);
        st[hf][1] = __builtin_amdgcn_mfma_f32_16x16x32_f16(ka[dk], aq[1][dk], st[hf][1], 0, 0, 0);
      }
    }
    __builtin_amdgcn_s_setprio(0);

    if (hasMask && n >= 4 * qb) {
#pragma unroll
      for (int mi = 0; mi < 2; mi++) {
        if (!os2[mi]) {
          int row = qb * 128 + wid * 32 + mi * 16 + c16;
#pragma unroll
          for (int hf = 0; hf < 2; hf++)
#pragma unroll
            for (int j = 0; j < 4; j++) {
              int tg = n * 32 + rg * 8 + hf * 4 + j;
              if (tg > row) st[hf][mi][j] = -1e30f;
            }
        }
      }
    }

#pragma unroll
    for (int mi = 0; mi < 2; mi++) {
      float mt = st[0][mi][0];
#pragma unroll
      for (int hf = 0; hf < 2; hf++)
#pragma unroll
        for (int j = 0; j < 4; j++)
          if (hf | j) mt = fmaxf(mt, st[hf][mi][j]);
      mt = fmaxf(mt, __shfl_xor(mt, 16, 64));
      mt = fmaxf(mt, __shfl_xor(mt, 32, 64));
      if (!__all(mt <= mrun[mi] + 8.f)) {
        float mnew = fmaxf(mrun[mi], mt);
        float sc = exp2f(mrun[mi] - mnew);
        mrun[mi] = mnew;
        lrun[mi] *= sc;
#pragma unroll
        for (int nf = 0; nf < 8; nf++) accO[mi][nf] *= sc;
      }
      float ps = 0.f;
#pragma unroll
      for (int hf = 0; hf < 2; hf++)
#pragma unroll
        for (int j = 0; j < 4; j++) {
          float p = exp2f(st[hf][mi][j] - mrun[mi]);
          st[hf][mi][j] = p;
          ps += p;
        }
      ps += __shfl_xor(ps, 16, 64);
      ps += __shfl_xor(ps, 32, 64);
      lrun[mi] += ps;
    }

    half8 pa[2];
#pragma unroll
    for (int mi = 0; mi < 2; mi++) {
      union { half8 v; _Float16 e[8]; } pu;
#pragma unroll
      for (int hf = 0; hf < 2; hf++)
#pragma unroll
        for (int j = 0; j < 4; j++)
          pu.e[hf * 4 + j] = (_Float16)st[hf][mi][j];
      pa[mi] = pu.v;
    }

    __builtin_amdgcn_s_setprio(1);
#pragma unroll
    for (int nf = 0; nf < 8; nf++) {
      half8 va = *(const half8*)(lb + 4096 + nf * 512 + lane * 8);
      accO[0][nf] = __builtin_amdgcn_mfma_f32_16x16x32_f16(va, pa[0], accO[0][nf], 0, 0, 0);
      accO[1][nf] = __builtin_amdgcn_mfma_f32_16x16x32_f16(va, pa[1], accO[1][nf], 0, 0, 0);
    }
    __builtin_amdgcn_s_setprio(0);
  }

  const int pidx = h * 80 + cidx(qb) + chunk;
  u16* pob = po + (size_t)pidx * 16384;
#pragma unroll
  for (int mi = 0; mi < 2; mi++) {
    float inv = 1.0f / lrun[mi];
    int row = wid * 32 + mi * 16 + c16;
#pragma unroll
    for (int nf = 0; nf < 8; nf++) {
      u32 p0 = (u32)f2h(accO[mi][nf][0] * inv) | ((u32)f2h(accO[mi][nf][1] * inv) << 16);
      u32 p1 = (u32)f2h(accO[mi][nf][2] * inv) | ((u32)f2h(accO[mi][nf][3] * inv) << 16);
      *(uint2*)&pob[row * 128 + nf * 16 + rg * 4] = make_uint2(p0, p1);
    }
    if (rg == 0)
      ml[(size_t)pidx * 128 + row] = mrun[mi] + log2f(lrun[mi]);
  }
}

// ---------------- combine split-KV partials -> attn (f16) ----------------
__global__ __launch_bounds__(256) void k_attn_combine(
    const u16* __restrict__ po, const float* __restrict__ ml, u16* __restrict__ attn) {
  const int qb = blockIdx.x, h = blockIdx.y;
  const int nc = (qb < 8) ? 1 : (qb < 16) ? 2 : (qb < 24) ? 3 : 4;
  const int base = h * 80 + cidx(qb);
  const int tid = threadIdx.x;
  const int r = tid >> 1, h64 = (tid & 1) * 64;
  float mp[4], M = -1e30f;
#pragma unroll
  for (int ci = 0; ci < 4; ci++) {
    mp[ci] = (ci < nc) ? ml[(size_t)(base + ci) * 128 + r] : -1e30f;
    M = fmaxf(M, mp[ci]);
  }
  float w[4], Ws = 0.f;
#pragma unroll
  for (int ci = 0; ci < 4; ci++) { w[ci] = exp2f(mp[ci] - M); Ws += (ci < nc) ? w[ci] : 0.f; }
  float inv = 1.0f / Ws;
  for (int d = 0; d < 64; d += 4) {
    float a[4] = {0.f, 0.f, 0.f, 0.f};
#pragma unroll
    for (int ci = 0; ci < 4; ci++) {
      if (ci < nc) {
        uint2 u = *(const uint2*)&po[(size_t)(base + ci) * 16384 + r * 128 + h64 + d];
        a[0] += w[ci] * h2f((u16)(u.x & 0xffff));
        a[1] += w[ci] * h2f((u16)(u.x >> 16));
        a[2] += w[ci] * h2f((u16)(u.y & 0xffff));
        a[3] += w[ci] * h2f((u16)(u.y >> 16));
      }
    }
    u32 p0 = (u32)f2h(a[0] * inv) | ((u32)f2h(a[1] * inv) << 16);
    u32 p1 = (u32)f2h(a[2] * inv) | ((u32)f2h(a[3] * inv) << 16);
    *(uint2*)&attn[(size_t)(qb * 128 + r) * DIMM + h * 128 + h64 + d] = make_uint2(p0, p1);
  }
}

// ---------------- out = attn @ wo (f16 GEMM, fp32 out, BK=64 DBUF stage-early, XCD-swizzled) ----------------
__global__ __launch_bounds__(256) void k_gemm_out(
    const u16* __restrict__ attn, const u16* __restrict__ wot, float* __restrict__ out) {
  __shared__ u16 lds[2][16384];  // per buf: A(128x64) | B(128x64) u16, 32KB; dbuf 64KB
  const int tid = threadIdx.x;
  const int lane = tid & 63, wid = tid >> 6;
  const int rg = lane >> 4, c16 = lane & 15;
  const int bid0 = blockIdx.y * 16 + blockIdx.x;           // 512 blocks
  const int swz = (bid0 & 7) * 64 + (bid0 >> 3);
  const int m0 = (swz >> 4) * 128, n0 = (swz & 15) * 128;
  const int wm = wid >> 1, wn = wid & 1;
  const u16* gsrc = (wid < 2) ? attn + (size_t)m0 * 2048 : wot + (size_t)n0 * 2048;
  const int sr = lane >> 3, scn = lane & 7;

  f32x4 acc[4][4];
#pragma unroll
  for (int a = 0; a < 4; a++)
#pragma unroll
    for (int b = 0; b < 4; b++) acc[a][b] = (f32x4){0.f, 0.f, 0.f, 0.f};

  auto stage = [&](int bi, int k0) {
#pragma unroll
    for (int i = 0; i < 8; i++) {
      int slot = wid * 8 + i;          // [0,32): 0..15 A, 16..31 B
      int s2 = slot & 15;
      int r = s2 * 8 + sr;
      int cs = (scn ^ (r & 7)) * 8;
      gll16(gsrc + (size_t)r * 2048 + k0 + cs, &lds[bi][slot * 512]);
    }
  };

  stage(0, 0);

  for (int ks = 0; ks < 32; ks++) {
    __syncthreads();                 // buf[ks&1] staged; prev buf's reads done
    if (ks + 1 < 32) stage((ks & 1) ^ 1, (ks + 1) * 64);  // overlap with this step's compute
    const u16* lb = lds[ks & 1];
#pragma unroll
    for (int kk = 0; kk < 2; kk++) {
      half8 a[4], b[4];
      int ch = kk * 4 + rg;
#pragma unroll
      for (int mf = 0; mf < 4; mf++) {
        int m = wm * 64 + mf * 16 + c16;
        a[mf] = *(const half8*)(lb + m * 64 + ((ch ^ (m & 7)) * 8));
      }
#pragma unroll
      for (int nf = 0; nf < 4; nf++) {
        int n = wn * 64 + nf * 16 + c16;
        b[nf] = *(const half8*)(lb + 8192 + n * 64 + ((ch ^ (n & 7)) * 8));
      }
      __builtin_amdgcn_s_setprio(1);
#pragma unroll
      for (int mf = 0; mf < 4; mf++)
#pragma unroll
        for (int nf = 0; nf < 4; nf++)
          acc[mf][nf] = __builtin_amdgcn_mfma_f32_16x16x32_f16(a[mf], b[nf], acc[mf][nf], 0, 0, 0);
      __builtin_amdgcn_s_setprio(0);
    }
  }
#pragma unroll
  for (int mf = 0; mf < 4; mf++)
#pragma unroll
    for (int nf = 0; nf < 4; nf++)
#pragma unroll
      for (int j = 0; j < 4; j++) {
        int m = m0 + wm * 64 + mf * 16 + rg * 4 + j;
        int n = n0 + wn * 64 + nf * 16 + c16;
        out[(size_t)m * DIMM + n] = acc[mf][nf][j];
      }
}

extern "C" void kernel_launch(void* const* d_in, const int* in_sizes, int n_in,
                              void* d_out, int out_size, void* d_ws, size_t ws_size,
                              hipStream_t stream) {
  (void)in_sizes; (void)n_in; (void)out_size; (void)ws_size;
  const float* x  = (const float*)d_in[0];
  const float* wq = (const float*)d_in[1];
  const float* wk = (const float*)d_in[2];
  const float* wv = (const float*)d_in[3];
  const float* wo = (const float*)d_in[4];
  float* out = (float*)d_out;

  char* ws = (char*)d_ws;
  const size_t MB = 1024 * 1024;
  // Region A (128MB): xh|xl|wth|wtl|qkv during projection; aliased by po|ml for split-KV
  char* A = ws;
  u16*   xh  = (u16*)(A);
  u16*   xl  = (u16*)(A + 16 * MB);
  u16*   wth = (u16*)(A + 32 * MB);
  u16*   wtl = (u16*)(A + 48 * MB);
  float* qkv = (float*)(A + 64 * MB);
  u16*   po  = (u16*)(A);              // 40MB (1280 x 128 x 128 f16), overlays dead buffers
  float* ml  = (float*)(A + 48 * MB);  // 0.64MB, overlays dead wtl
  // Region B (persistent)
  char* B = ws + 128 * MB;
  size_t off = 0;
  auto alloc = [&](size_t b) { char* p = B + off; off += (b + 255) & ~(size_t)255; return p; };
  u16*   wot  = (u16*)alloc((size_t)DIMM * DIMM * 2);
  float* cosb = (float*)alloc((size_t)SQ * 64 * 4);
  float* sinb = (float*)alloc((size_t)SQ * 64 * 4);
  u16*   qf   = (u16*)alloc((size_t)16 * SQ * 128 * 2);
  u16*   kf2  = (u16*)alloc((size_t)8 * SQ * 128 * 2);
  u16*   vt2  = (u16*)alloc((size_t)8 * 128 * SQ * 2);
  float* bm   = (float*)alloc((size_t)8 * 32 * 128 * 4);
  unsigned char* sel = (unsigned char*)alloc((size_t)16 * SQ);
  u16*   attn = (u16*)alloc((size_t)SQ * DIMM * 2);

  k_prep1<<<12288, 256, 0, stream>>>(x, wq, wk, wv, wo, cosb, sinb, xh, xl, wth, wtl, wot);
  k_gemm_qkv<<<dim3(32, 32), 256, 0, stream>>>(xh, xl, wth, wtl, qkv);
  k_prep2<<<5184, 256, 0, stream>>>(qkv, cosb, sinb, qf, kf2, vt2, bm);
  k_gate<<<16 * 48, 64, 0, stream>>>(qkv, cosb, sinb, bm, sel);
  // qkv (and xh/xl/wth/wtl) are dead past this point -> po/ml alias them
  k_attn_chunk<<<1280, 256, 0, stream>>>(qf, kf2, vt2, sel, po, ml);
  k_attn_combine<<<dim3(32, 16), 256, 0, stream>>>(po, ml, attn);
  k_gemm_out<<<dim3(16, 32), 256, 0, stream>>>(attn, wot, out);
}